// Round 18
// baseline (112.027 us; speedup 1.0000x reference)
//
#include <hip/hip_runtime.h>
#include <hip/hip_bf16.h>

typedef __attribute__((ext_vector_type(8))) short short8;
typedef __attribute__((ext_vector_type(4))) short short4v;
typedef __attribute__((ext_vector_type(4))) float f32x4;

#define LN10000_DIV32 0.2878231366242558f
#define SCALE_Q_LOG2E 0.18033688011112042f
#define EXP_BIAS 12.0f

__device__ __forceinline__ unsigned short f2bf(float f){
  union { float fv; unsigned u; } a; a.fv = f;
  return (unsigned short)((a.u + 0x7fffu + ((a.u >> 16) & 1u)) >> 16);
}

// ------- convert fp32 -> bf16 (x, W_Q|W_K|W_V, W_O) + RoPE cos/sin table -------
__global__ __launch_bounds__(256) void convert_all(
    const float* __restrict__ x, const float* __restrict__ wq,
    const float* __restrict__ wk, const float* __restrict__ wv,
    const float* __restrict__ wo, unsigned short* __restrict__ dst,
    float2* __restrict__ tab)
{
  size_t t = (size_t)blockIdx.x * 256 + threadIdx.x;
  if (t < 65536UL){
    const int s = (int)(t >> 5), ip = (int)(t & 31);
    float invf = __expf(-(float)ip * LN10000_DIV32);
    float ang = (float)s * invf;
    tab[t] = make_float2(__cosf(ang), __sinf(ang));
  }
  size_t e = t * 8;
  const float* src; size_t off;
  if (e < 4194304UL)      { src = x;  off = e; }
  else if (e < 5242880UL) { src = wq; off = e - 4194304UL; }
  else if (e < 6291456UL) { src = wk; off = e - 5242880UL; }
  else if (e < 7340032UL) { src = wv; off = e - 6291456UL; }
  else                    { src = wo; off = e - 7340032UL; }
  float4 f0 = *(const float4*)(src + off);
  float4 f1 = *(const float4*)(src + off + 4);
  short8 o;
  o[0] = (short)f2bf(f0.x); o[1] = (short)f2bf(f0.y);
  o[2] = (short)f2bf(f0.z); o[3] = (short)f2bf(f0.w);
  o[4] = (short)f2bf(f1.x); o[5] = (short)f2bf(f1.y);
  o[6] = (short)f2bf(f1.z); o[7] = (short)f2bf(f1.w);
  *(short8*)(dst + e) = o;
}

// ---------------- QKV projection: 128x192 tile, BK=64, 1-barrier burst (R17, frozen) ----------------
__global__ __launch_bounds__(256, 2) void gemm_qkv(
    const unsigned short* __restrict__ Xb, const unsigned short* __restrict__ Wb,
    const int* __restrict__ positions, const float2* __restrict__ tab,
    unsigned short* __restrict__ Qb, unsigned short* __restrict__ Kb,
    unsigned short* __restrict__ Vtb)
{
  __shared__ __align__(16) unsigned short As[2*8192];   // 2 x 128x64 (32 KB)
  __shared__ __align__(16) unsigned short Bs[2*12288];  // 2 x 192x64 (48 KB)
  f32x4 acc[4][6] = {};
  const int tid = threadIdx.x, lane = tid & 63, w = tid >> 6;
  const int wm = w >> 1, wn = w & 1;
  const int fr = lane & 15, fq = lane >> 4;
  const int id  = blockIdx.x;                           // 0..511
  const int xcd = id & 7;
  const int lid = id >> 3;                              // 0..63
  const int m0 = (lid & 31) * 128;
  const int n0 = (xcd*2 + (lid >> 5)) * 192;

#define STAGE_ALL(kt, buf) do {                                                     \
    _Pragma("unroll")                                                               \
    for (int i_ = 0; i_ < 4; ++i_){                    /* A: 1024 chunks */         \
      const int c_ = i_*256 + tid;                                                  \
      const int row_ = c_ >> 3, cd_ = c_ & 7;                                       \
      const int sc_ = (cd_ ^ (row_ & 7)) << 3;                                      \
      const unsigned short* ga_ = Xb + (size_t)(m0 + row_) * 1024 + (kt)*64 + sc_;  \
      __builtin_amdgcn_global_load_lds((const __attribute__((address_space(1))) void*)ga_, \
          (__attribute__((address_space(3))) void*)(As + (buf)*8192 + c_*8), 16, 0, 0);    \
    }                                                                               \
    _Pragma("unroll")                                                               \
    for (int i_ = 0; i_ < 6; ++i_){                    /* B: 1536 chunks */         \
      const int c_ = i_*256 + tid;                                                  \
      const int row_ = c_ >> 3, cd_ = c_ & 7;                                       \
      const int sc_ = (cd_ ^ (row_ & 7)) << 3;                                      \
      const unsigned short* gb_ = Wb + (size_t)(n0 + row_) * 1024 + (kt)*64 + sc_;  \
      __builtin_amdgcn_global_load_lds((const __attribute__((address_space(1))) void*)gb_, \
          (__attribute__((address_space(3))) void*)(Bs + (buf)*12288 + c_*8), 16, 0, 0);   \
    }                                                                               \
  } while(0)

  STAGE_ALL(0, 0);

  const int row_a0 = wm*64 + fr;
  const int row_b0 = wn*96 + fr;

  for (int t = 0; t < 16; ++t){
    const int cur = t & 1;
    asm volatile("s_waitcnt vmcnt(0)" ::: "memory");
    __builtin_amdgcn_s_barrier();
    asm volatile("" ::: "memory");
    if (t + 1 < 16) STAGE_ALL(t + 1, cur ^ 1);
    const unsigned short* as = As + cur*8192;
    const unsigned short* bs = Bs + cur*12288;
    short8 af[4], bfv[6];

#define LDA(mf_, kh_) do { \
      const int row_ = row_a0 + (mf_)*16; \
      const int c_ = ((kh_)*4 + fq) ^ (row_ & 7); \
      af[mf_] = *(const short8*)(as + row_*64 + c_*8); } while(0)
#define LDB(nf_, kh_) do { \
      const int row_ = row_b0 + (nf_)*16; \
      const int c_ = ((kh_)*4 + fq) ^ (row_ & 7); \
      bfv[nf_] = *(const short8*)(bs + row_*64 + c_*8); } while(0)

    LDA(0,0); LDA(1,0); LDA(2,0); LDA(3,0);
    LDB(0,0); LDB(1,0); LDB(2,0); LDB(3,0); LDB(4,0); LDB(5,0);
    __builtin_amdgcn_s_setprio(1);
    #pragma unroll
    for (int mf = 0; mf < 4; ++mf)
      #pragma unroll
      for (int nf = 0; nf < 6; ++nf)
        acc[mf][nf] = __builtin_amdgcn_mfma_f32_16x16x32_bf16(af[mf], bfv[nf], acc[mf][nf], 0, 0, 0);
    __builtin_amdgcn_s_setprio(0);

    LDA(0,1); LDA(1,1); LDA(2,1); LDA(3,1);
    LDB(0,1); LDB(1,1); LDB(2,1); LDB(3,1); LDB(4,1); LDB(5,1);
    __builtin_amdgcn_s_setprio(1);
    #pragma unroll
    for (int mf = 0; mf < 4; ++mf)
      #pragma unroll
      for (int nf = 0; nf < 6; ++nf)
        acc[mf][nf] = __builtin_amdgcn_mfma_f32_16x16x32_bf16(af[mf], bfv[nf], acc[mf][nf], 0, 0, 0);
    __builtin_amdgcn_s_setprio(0);
    asm volatile("" ::: "memory");
#undef LDA
#undef LDB
  }
#undef STAGE_ALL

  #pragma unroll
  for (int mf = 0; mf < 4; ++mf){
    int pm[4];
    #pragma unroll
    for (int r = 0; r < 4; ++r){
      const int m = m0 + wm*64 + mf*16 + fq*4 + r;
      pm[r] = positions[m] & 2047;
    }
    const int mbase = m0 + wm*64 + mf*16 + fq*4;
    const int b = mbase >> 11;
    const int s0 = mbase & 2047;
    #pragma unroll
    for (int nf = 0; nf < 6; ++nf){
      const int n = n0 + wn*96 + nf*16 + fr;
      const int seg = n >> 10;
      const int h = (n & 1023) >> 6, d = n & 63;
      const size_t bh = (size_t)b * 16 + h;
      if (seg == 2){
        short4v pack;
        #pragma unroll
        for (int r = 0; r < 4; ++r)
          pack[r] = (short)f2bf(acc[mf][nf][r]);
        *(short4v*)&Vtb[(bh*64 + d)*2048 + s0] = pack;
      } else {
        const int ip = d >> 1;
        #pragma unroll
        for (int r = 0; r < 4; ++r){
          float v = acc[mf][nf][r];
          float pv = __shfl_xor(v, 1);
          const float2 cs = tab[(pm[r] << 5) + ip];
          float outv = (d & 1) ? (cs.x * v + cs.y * pv)
                               : (cs.x * v - cs.y * pv);
          if (seg == 0) outv *= SCALE_Q_LOG2E;
          const unsigned short ob = f2bf(outv);
          const int s = s0 + r;
          if (seg == 0) Qb[(bh*2048 + s)*64 + d] = ob;
          else          Kb[(bh*2048 + s)*64 + d] = ob;
        }
      }
    }
  }
}

// ---------------- causal flash attention v7 ----------------
// 1024 blocks x 128 threads (2 waves x 32 q-rows). Same 4-blocks/CU co-residency as v6
// (LDS exactly 40 KB), but V/K fragment reads amortized over two q-halves per wave:
// 20 ds_read_b128 per 32 MFMA (was 18 per 16). Fixed-bias softmax (v6, proven).
__global__ __launch_bounds__(128) void attn_kernel(
    const unsigned short* __restrict__ Qb, const unsigned short* __restrict__ Kb,
    const unsigned short* __restrict__ Vtb, unsigned short* __restrict__ Ob)
{
  __shared__ __align__(16) unsigned short Ks[2][4096];
  __shared__ __align__(16) unsigned short Vs[2][4096];
  __shared__ __align__(16) unsigned short Plds[2][32][64];

  const int tid = threadIdx.x, lane = tid & 63, w = tid >> 6;   // w in {0,1}
  const int fr = lane & 15, fq = lane >> 4;

  const int i = blockIdx.x;
  const int bh = (i & 7) | (((i >> 3) & 3) << 3);   // XCD-pinned
  const int tile = 31 - (i >> 5);                   // longest tiles first
  const int b = bh >> 4, h = bh & 15;
  const int q0 = tile * 64 + w * 32;                // this wave's 32 q rows
  const size_t qk_base = (size_t)bh * 2048 * 64;
  const unsigned short* kbase = Kb + qk_base;
  const unsigned short* vbase = Vtb + (size_t)bh * 64 * 2048;

  // Q fragments (B-operand) for both 16-row halves; Q pre-scaled by 0.125*log2e
  short8 aq[2][2];
  #pragma unroll
  for (int qh = 0; qh < 2; ++qh){
    const unsigned short* qp = Qb + qk_base + (size_t)(q0 + qh*16 + fr) * 64 + fq * 8;
    aq[qh][0] = *(const short8*)qp;
    aq[qh][1] = *(const short8*)(qp + 32);
  }

  f32x4 accO[2][4] = {};
  float lrun[2] = {0.f, 0.f};
  const int nt = tile + 1;
  const int sw3 = (fr & 7) << 2;

#define STAGE_KV(t_, buf_) do {                                                     \
    const int kv0_ = (t_) * 64;                                                     \
    _Pragma("unroll")                                                               \
    for (int ii_ = 0; ii_ < 4; ++ii_){                                              \
      const int chunk_ = ii_ * 128 + tid;            /* 512 chunks each */          \
      const int row_ = chunk_ >> 3, cd_ = chunk_ & 7;                               \
      const int sc_ = (cd_ ^ (row_ & 7)) << 3;                                      \
      const unsigned short* ksrc_ = kbase + (size_t)(kv0_ + row_) * 64 + sc_;       \
      const unsigned short* vsrc_ = vbase + (size_t)row_ * 2048 + kv0_ + sc_;       \
      __builtin_amdgcn_global_load_lds((const __attribute__((address_space(1))) void*)ksrc_, \
          (__attribute__((address_space(3))) void*)(&Ks[buf_][0] + chunk_*8), 16, 0, 0);     \
      __builtin_amdgcn_global_load_lds((const __attribute__((address_space(1))) void*)vsrc_, \
          (__attribute__((address_space(3))) void*)(&Vs[buf_][0] + chunk_*8), 16, 0, 0);     \
    }                                                                               \
  } while(0)

  STAGE_KV(0, 0);
  for (int t = 0; t < nt; ++t){
    const int cur = t & 1;
    const int kv0 = t * 64;
    if (t + 1 < nt){
      STAGE_KV(t + 1, cur ^ 1);
      asm volatile("s_waitcnt vmcnt(8)" ::: "memory");   // tile t's 8 loads done
    } else {
      asm volatile("s_waitcnt vmcnt(0)" ::: "memory");
    }
    __builtin_amdgcn_s_barrier();
    asm volatile("" ::: "memory");
    const unsigned short* ks = &Ks[cur][0];
    const unsigned short* vs = &Vs[cur][0];

    // ---- S^T = K·Q^T for both q-halves: K fragments read once, used twice ----
    f32x4 sT[4][2];
    #pragma unroll
    for (int kf = 0; kf < 4; ++kf){
      const int row = kf*16 + fr;
      const int swr = row & 7;
      short8 k0 = *(const short8*)(ks + row*64 + ((fq ^ swr) << 3));
      short8 k1 = *(const short8*)(ks + row*64 + (((4 + fq) ^ swr) << 3));
      #pragma unroll
      for (int qh = 0; qh < 2; ++qh){
        f32x4 s = {0.f, 0.f, 0.f, 0.f};
        s = __builtin_amdgcn_mfma_f32_16x16x32_bf16(k0, aq[qh][0], s, 0, 0, 0);
        s = __builtin_amdgcn_mfma_f32_16x16x32_bf16(k1, aq[qh][1], s, 0, 0, 0);
        sT[kf][qh] = s;
      }
    }
    // ---- causal mask: only the final tile ----
    if (t == nt - 1){
      #pragma unroll
      for (int qh = 0; qh < 2; ++qh){
        const int qrow = q0 + qh*16 + fr;
        #pragma unroll
        for (int kf = 0; kf < 4; ++kf)
          #pragma unroll
          for (int r = 0; r < 4; ++r){
            const int kvcol = kv0 + kf*16 + fq*4 + r;
            if (kvcol > qrow) sT[kf][qh][r] = -1e30f;
          }
      }
    }
    // ---- fixed-bias softmax per half + P pack ----
    #pragma unroll
    for (int qh = 0; qh < 2; ++qh){
      float p[4][4];
      float rs = 0.f;
      #pragma unroll
      for (int kf = 0; kf < 4; ++kf)
        #pragma unroll
        for (int r = 0; r < 4; ++r){
          p[kf][r] = __builtin_amdgcn_exp2f(sT[kf][qh][r] - EXP_BIAS);
          rs += p[kf][r];
        }
      rs += __shfl_xor(rs, 16);
      rs += __shfl_xor(rs, 32);
      lrun[qh] += rs;
      unsigned* prow = (unsigned*)&Plds[w][qh*16 + fr][0];
      #pragma unroll
      for (int kf = 0; kf < 4; ++kf)
        #pragma unroll
        for (int jj = 0; jj < 2; ++jj){
          unsigned pk;
          asm("v_cvt_pk_bf16_f32 %0, %1, %2" : "=v"(pk) : "v"(p[kf][2*jj]), "v"(p[kf][2*jj+1]));
          prow[(kf*8 + fq*2 + jj) ^ sw3] = pk;
        }
    }
    asm volatile("s_waitcnt lgkmcnt(0)" ::: "memory");
    short8 ap[2][2];
    #pragma unroll
    for (int qh = 0; qh < 2; ++qh){
      const unsigned* crow = (const unsigned*)&Plds[w][qh*16 + fr][0];
      ap[qh][0] = *(const short8*)&crow[(fq*4) ^ sw3];
      ap[qh][1] = *(const short8*)&crow[(16 + fq*4) ^ sw3];
    }
    // ---- O += P * V : V fragments read once, used by both halves ----
    __builtin_amdgcn_s_setprio(1);
    #pragma unroll
    for (int dblk = 0; dblk < 4; ++dblk){
      const int d = dblk*16 + fr;
      const int swd = d & 7;
      short8 bv0 = *(const short8*)(vs + d*64 + ((fq ^ swd) << 3));
      short8 bv1 = *(const short8*)(vs + d*64 + (((4 + fq) ^ swd) << 3));
      #pragma unroll
      for (int qh = 0; qh < 2; ++qh){
        accO[qh][dblk] = __builtin_amdgcn_mfma_f32_16x16x32_bf16(ap[qh][0], bv0, accO[qh][dblk], 0, 0, 0);
        accO[qh][dblk] = __builtin_amdgcn_mfma_f32_16x16x32_bf16(ap[qh][1], bv1, accO[qh][dblk], 0, 0, 0);
      }
    }
    __builtin_amdgcn_s_setprio(0);
    asm volatile("" ::: "memory");
    __builtin_amdgcn_s_barrier();
  }
#undef STAGE_KV
  // ---- epilogue per half ----
  #pragma unroll
  for (int qh = 0; qh < 2; ++qh){
    float lq[4];
    #pragma unroll
    for (int r = 0; r < 4; ++r)
      lq[r] = __shfl(lrun[qh], fq*4 + r);
    #pragma unroll
    for (int dblk = 0; dblk < 4; ++dblk)
      #pragma unroll
      for (int r = 0; r < 4; ++r){
        const int s = q0 + qh*16 + fq*4 + r;
        const float o = accO[qh][dblk][r] / lq[r];
        Ob[((size_t)b*2048 + s)*1024 + h*64 + dblk*16 + fr] = f2bf(o);
      }
  }
}

// ---------------- output projection -> fp32 d_out (round-11/12, frozen) ----------------
__global__ __launch_bounds__(256) void gemm_out(
    const unsigned short* __restrict__ Obf, const unsigned short* __restrict__ Wb,
    float* __restrict__ out)
{
  __shared__ __align__(16) unsigned short As[3*4096];
  __shared__ __align__(16) unsigned short Bs[3*2048];
  f32x4 acc[4][2] = {};
  const int tid = threadIdx.x, lane = tid & 63, w = tid >> 6;
  const int wm = w >> 1, wn = w & 1;
  const int fr = lane & 15, fq = lane >> 4;
  const int id  = blockIdx.x;            // 0..511
  const int xcd = id & 7;
  const int lid = id >> 3;               // 0..63
  const int m0 = (xcd*4 + (lid & 3)) * 128;
  const int n0 = (lid >> 2) * 64;
  const int ph = ((fq ^ ((fr + (fr >> 2)) & 3))) * 8;

#define STAGEO(kt, buf) do {                                                        \
    _Pragma("unroll")                                                               \
    for (int i_ = 0; i_ < 2; ++i_){                                                 \
      const int c_ = i_*256 + tid;                                                  \
      const int row_ = c_ >> 2, cd_ = c_ & 3;                                       \
      const int sc_ = ((cd_ ^ ((row_ + (row_ >> 2)) & 3))) << 3;                    \
      const unsigned short* ga_ = Obf + (size_t)(m0 + row_) * 1024 + (kt)*32 + sc_; \
      __builtin_amdgcn_global_load_lds((const __attribute__((address_space(1))) void*)ga_, \
          (__attribute__((address_space(3))) void*)(As + (buf)*4096 + c_*8), 16, 0, 0);    \
    }                                                                               \
    {                                                                               \
      const int c_ = tid;                                                           \
      const int row_ = c_ >> 2, cd_ = c_ & 3;                                       \
      const int sc_ = ((cd_ ^ ((row_ + (row_ >> 2)) & 3))) << 3;                    \
      const unsigned short* gb_ = Wb + (size_t)(n0 + row_) * 1024 + (kt)*32 + sc_;  \
      __builtin_amdgcn_global_load_lds((const __attribute__((address_space(1))) void*)gb_, \
          (__attribute__((address_space(3))) void*)(Bs + (buf)*2048 + c_*8), 16, 0, 0);    \
    }                                                                               \
  } while(0)

  STAGEO(0, 0);
  STAGEO(1, 1);
  for (int t = 0; t < 32; ++t){
    const int cur = t % 3;
    if (t + 2 < 32) STAGEO(t + 2, (t + 2) % 3);
    if (t < 30)       asm volatile("s_waitcnt vmcnt(6)" ::: "memory");
    else if (t == 30) asm volatile("s_waitcnt vmcnt(3)" ::: "memory");
    else              asm volatile("s_waitcnt vmcnt(0)" ::: "memory");
    __builtin_amdgcn_s_barrier();
    asm volatile("" ::: "memory");
    const unsigned short* as = As + cur*4096;
    const unsigned short* bs = Bs + cur*2048;
    short8 af[4], bfv[2];
    #pragma unroll
    for (int mf = 0; mf < 4; ++mf)
      af[mf] = *(const short8*)(as + (wm*64 + mf*16 + fr) * 32 + ph);
    #pragma unroll
    for (int nf = 0; nf < 2; ++nf)
      bfv[nf] = *(const short8*)(bs + (wn*32 + nf*16 + fr) * 32 + ph);
    #pragma unroll
    for (int mf = 0; mf < 4; ++mf)
      #pragma unroll
      for (int nf = 0; nf < 2; ++nf)
        acc[mf][nf] = __builtin_amdgcn_mfma_f32_16x16x32_bf16(af[mf], bfv[nf], acc[mf][nf], 0, 0, 0);
    asm volatile("" ::: "memory");
    __builtin_amdgcn_s_barrier();
  }
#undef STAGEO

  #pragma unroll
  for (int mf = 0; mf < 4; ++mf)
    #pragma unroll
    for (int nf = 0; nf < 2; ++nf){
      const int n = n0 + wn*32 + nf*16 + fr;
      #pragma unroll
      for (int r = 0; r < 4; ++r){
        const int m = m0 + wm*64 + mf*16 + fq*4 + r;
        out[(size_t)m * 1024 + n] = acc[mf][nf][r];
      }
    }
}

extern "C" void kernel_launch(void* const* d_in, const int* in_sizes, int n_in,
                              void* d_out, int out_size, void* d_ws, size_t ws_size,
                              hipStream_t stream) {
  const float* x  = (const float*)d_in[0];
  const int* pos  = (const int*)d_in[1];
  const float* wq = (const float*)d_in[2];
  const float* wk = (const float*)d_in[3];
  const float* wv = (const float*)d_in[4];
  const float* wo = (const float*)d_in[5];
  float* out = (float*)d_out;

  unsigned short* ws = (unsigned short*)d_ws;
  unsigned short* Xb   = ws;                  // 4096x1024
  unsigned short* Wqkv = ws + 4194304UL;      // 3072x1024
  unsigned short* Wo   = ws + 7340032UL;      // 1024x1024
  unsigned short* Qb   = ws + 8388608UL;      // [32][2048][64]
  unsigned short* Kb   = ws + 12582912UL;     // [32][2048][64]
  unsigned short* Vt   = ws + 16777216UL;     // [32][64][2048]
  unsigned short* Ob   = ws + 20971520UL;     // 4096x1024
  float2* tab          = (float2*)(ws + 25165824UL);  // 2048x32 cos/sin (512 KB)

  convert_all<<<4096, 256, 0, stream>>>(x, wq, wk, wv, wo, ws, tab);

  gemm_qkv<<<512, 256, 0, stream>>>(Xb, Wqkv, pos, tab, Qb, Kb, Vt);

  attn_kernel<<<1024, 128, 0, stream>>>(Qb, Kb, Vt, Ob);

  gemm_out<<<512, 256, 0, stream>>>(Ob, Wo, out);
}

// Round 19
// 104.765 us; speedup vs baseline: 1.0693x; 1.0693x over previous
//
#include <hip/hip_runtime.h>
#include <hip/hip_bf16.h>

typedef __attribute__((ext_vector_type(8))) short short8;
typedef __attribute__((ext_vector_type(4))) short short4v;
typedef __attribute__((ext_vector_type(4))) float f32x4;

#define LN10000_DIV32 0.2878231366242558f
#define SCALE_Q_LOG2E 0.18033688011112042f
#define EXP_BIAS 12.0f

__device__ __forceinline__ unsigned short f2bf(float f){
  union { float fv; unsigned u; } a; a.fv = f;
  return (unsigned short)((a.u + 0x7fffu + ((a.u >> 16) & 1u)) >> 16);
}

// ------- convert fp32 -> bf16 (x, W_Q|W_K|W_V, W_O) + RoPE cos/sin table -------
__global__ __launch_bounds__(256) void convert_all(
    const float* __restrict__ x, const float* __restrict__ wq,
    const float* __restrict__ wk, const float* __restrict__ wv,
    const float* __restrict__ wo, unsigned short* __restrict__ dst,
    float2* __restrict__ tab)
{
  size_t t = (size_t)blockIdx.x * 256 + threadIdx.x;
  if (t < 65536UL){
    const int s = (int)(t >> 5), ip = (int)(t & 31);
    float invf = __expf(-(float)ip * LN10000_DIV32);
    float ang = (float)s * invf;
    tab[t] = make_float2(__cosf(ang), __sinf(ang));
  }
  size_t e = t * 8;
  const float* src; size_t off;
  if (e < 4194304UL)      { src = x;  off = e; }
  else if (e < 5242880UL) { src = wq; off = e - 4194304UL; }
  else if (e < 6291456UL) { src = wk; off = e - 5242880UL; }
  else if (e < 7340032UL) { src = wv; off = e - 6291456UL; }
  else                    { src = wo; off = e - 7340032UL; }
  float4 f0 = *(const float4*)(src + off);
  float4 f1 = *(const float4*)(src + off + 4);
  short8 o;
  o[0] = (short)f2bf(f0.x); o[1] = (short)f2bf(f0.y);
  o[2] = (short)f2bf(f0.z); o[3] = (short)f2bf(f0.w);
  o[4] = (short)f2bf(f1.x); o[5] = (short)f2bf(f1.y);
  o[6] = (short)f2bf(f1.z); o[7] = (short)f2bf(f1.w);
  *(short8*)(dst + e) = o;
}

// ---------------- QKV projection: 128x192 tile, BK=64, 1-barrier burst (R17, frozen) ----------------
__global__ __launch_bounds__(256, 2) void gemm_qkv(
    const unsigned short* __restrict__ Xb, const unsigned short* __restrict__ Wb,
    const int* __restrict__ positions, const float2* __restrict__ tab,
    unsigned short* __restrict__ Qb, unsigned short* __restrict__ Kb,
    unsigned short* __restrict__ Vtb)
{
  __shared__ __align__(16) unsigned short As[2*8192];   // 2 x 128x64 (32 KB)
  __shared__ __align__(16) unsigned short Bs[2*12288];  // 2 x 192x64 (48 KB)
  f32x4 acc[4][6] = {};
  const int tid = threadIdx.x, lane = tid & 63, w = tid >> 6;
  const int wm = w >> 1, wn = w & 1;
  const int fr = lane & 15, fq = lane >> 4;
  const int id  = blockIdx.x;                           // 0..511
  const int xcd = id & 7;
  const int lid = id >> 3;                              // 0..63
  const int m0 = (lid & 31) * 128;
  const int n0 = (xcd*2 + (lid >> 5)) * 192;

#define STAGE_ALL(kt, buf) do {                                                     \
    _Pragma("unroll")                                                               \
    for (int i_ = 0; i_ < 4; ++i_){                    /* A: 1024 chunks */         \
      const int c_ = i_*256 + tid;                                                  \
      const int row_ = c_ >> 3, cd_ = c_ & 7;                                       \
      const int sc_ = (cd_ ^ (row_ & 7)) << 3;                                      \
      const unsigned short* ga_ = Xb + (size_t)(m0 + row_) * 1024 + (kt)*64 + sc_;  \
      __builtin_amdgcn_global_load_lds((const __attribute__((address_space(1))) void*)ga_, \
          (__attribute__((address_space(3))) void*)(As + (buf)*8192 + c_*8), 16, 0, 0);    \
    }                                                                               \
    _Pragma("unroll")                                                               \
    for (int i_ = 0; i_ < 6; ++i_){                    /* B: 1536 chunks */         \
      const int c_ = i_*256 + tid;                                                  \
      const int row_ = c_ >> 3, cd_ = c_ & 7;                                       \
      const int sc_ = (cd_ ^ (row_ & 7)) << 3;                                      \
      const unsigned short* gb_ = Wb + (size_t)(n0 + row_) * 1024 + (kt)*64 + sc_;  \
      __builtin_amdgcn_global_load_lds((const __attribute__((address_space(1))) void*)gb_, \
          (__attribute__((address_space(3))) void*)(Bs + (buf)*12288 + c_*8), 16, 0, 0);   \
    }                                                                               \
  } while(0)

  STAGE_ALL(0, 0);

  const int row_a0 = wm*64 + fr;
  const int row_b0 = wn*96 + fr;

  for (int t = 0; t < 16; ++t){
    const int cur = t & 1;
    asm volatile("s_waitcnt vmcnt(0)" ::: "memory");
    __builtin_amdgcn_s_barrier();
    asm volatile("" ::: "memory");
    if (t + 1 < 16) STAGE_ALL(t + 1, cur ^ 1);
    const unsigned short* as = As + cur*8192;
    const unsigned short* bs = Bs + cur*12288;
    short8 af[4], bfv[6];

#define LDA(mf_, kh_) do { \
      const int row_ = row_a0 + (mf_)*16; \
      const int c_ = ((kh_)*4 + fq) ^ (row_ & 7); \
      af[mf_] = *(const short8*)(as + row_*64 + c_*8); } while(0)
#define LDB(nf_, kh_) do { \
      const int row_ = row_b0 + (nf_)*16; \
      const int c_ = ((kh_)*4 + fq) ^ (row_ & 7); \
      bfv[nf_] = *(const short8*)(bs + row_*64 + c_*8); } while(0)

    LDA(0,0); LDA(1,0); LDA(2,0); LDA(3,0);
    LDB(0,0); LDB(1,0); LDB(2,0); LDB(3,0); LDB(4,0); LDB(5,0);
    __builtin_amdgcn_s_setprio(1);
    #pragma unroll
    for (int mf = 0; mf < 4; ++mf)
      #pragma unroll
      for (int nf = 0; nf < 6; ++nf)
        acc[mf][nf] = __builtin_amdgcn_mfma_f32_16x16x32_bf16(af[mf], bfv[nf], acc[mf][nf], 0, 0, 0);
    __builtin_amdgcn_s_setprio(0);

    LDA(0,1); LDA(1,1); LDA(2,1); LDA(3,1);
    LDB(0,1); LDB(1,1); LDB(2,1); LDB(3,1); LDB(4,1); LDB(5,1);
    __builtin_amdgcn_s_setprio(1);
    #pragma unroll
    for (int mf = 0; mf < 4; ++mf)
      #pragma unroll
      for (int nf = 0; nf < 6; ++nf)
        acc[mf][nf] = __builtin_amdgcn_mfma_f32_16x16x32_bf16(af[mf], bfv[nf], acc[mf][nf], 0, 0, 0);
    __builtin_amdgcn_s_setprio(0);
    asm volatile("" ::: "memory");
#undef LDA
#undef LDB
  }
#undef STAGE_ALL

  #pragma unroll
  for (int mf = 0; mf < 4; ++mf){
    int pm[4];
    #pragma unroll
    for (int r = 0; r < 4; ++r){
      const int m = m0 + wm*64 + mf*16 + fq*4 + r;
      pm[r] = positions[m] & 2047;
    }
    const int mbase = m0 + wm*64 + mf*16 + fq*4;
    const int b = mbase >> 11;
    const int s0 = mbase & 2047;
    #pragma unroll
    for (int nf = 0; nf < 6; ++nf){
      const int n = n0 + wn*96 + nf*16 + fr;
      const int seg = n >> 10;
      const int h = (n & 1023) >> 6, d = n & 63;
      const size_t bh = (size_t)b * 16 + h;
      if (seg == 2){
        short4v pack;
        #pragma unroll
        for (int r = 0; r < 4; ++r)
          pack[r] = (short)f2bf(acc[mf][nf][r]);
        *(short4v*)&Vtb[(bh*64 + d)*2048 + s0] = pack;
      } else {
        const int ip = d >> 1;
        #pragma unroll
        for (int r = 0; r < 4; ++r){
          float v = acc[mf][nf][r];
          float pv = __shfl_xor(v, 1);
          const float2 cs = tab[(pm[r] << 5) + ip];
          float outv = (d & 1) ? (cs.x * v + cs.y * pv)
                               : (cs.x * v - cs.y * pv);
          if (seg == 0) outv *= SCALE_Q_LOG2E;
          const unsigned short ob = f2bf(outv);
          const int s = s0 + r;
          if (seg == 0) Qb[(bh*2048 + s)*64 + d] = ob;
          else          Kb[(bh*2048 + s)*64 + d] = ob;
        }
      }
    }
  }
}

// ---------------- causal flash attention v6: fixed-bias softmax (proven best, restored) ----------------
__global__ __launch_bounds__(256) void attn_kernel(
    const unsigned short* __restrict__ Qb, const unsigned short* __restrict__ Kb,
    const unsigned short* __restrict__ Vtb, unsigned short* __restrict__ Ob)
{
  __shared__ __align__(16) unsigned short Ks[2][4096];
  __shared__ __align__(16) unsigned short Vs[2][4096];
  __shared__ __align__(16) unsigned short Plds[4][16][64];

  const int tid = threadIdx.x, lane = tid & 63, w = tid >> 6;
  const int fr = lane & 15, fq = lane >> 4;

  const int i = blockIdx.x;
  const int bh = (i & 7) | (((i >> 3) & 3) << 3);   // XCD-pinned
  const int tile = 31 - (i >> 5);                   // longest tiles first
  const int b = bh >> 4, h = bh & 15;
  const int q0 = tile * 64 + w * 16;
  const size_t qk_base = (size_t)bh * 2048 * 64;
  const unsigned short* kbase = Kb + qk_base;
  const unsigned short* vbase = Vtb + (size_t)bh * 64 * 2048;

  const unsigned short* qp = Qb + qk_base + (size_t)(q0 + fr) * 64 + fq * 8;
  short8 aq0 = *(const short8*)qp;
  short8 aq1 = *(const short8*)(qp + 32);

  f32x4 accO[4] = {};
  float lrun = 0.f;
  const int qrow = q0 + fr;
  const int nt = tile + 1;
  const int sw3 = (fr & 7) << 2;

#define STAGE_KV(t_, buf_) do {                                                     \
    const int kv0_ = (t_) * 64;                                                     \
    _Pragma("unroll")                                                               \
    for (int ii_ = 0; ii_ < 2; ++ii_){                                              \
      const int chunk_ = ii_ * 256 + tid;                                           \
      const int row_ = chunk_ >> 3, cd_ = chunk_ & 7;                               \
      const int sc_ = (cd_ ^ (row_ & 7)) << 3;                                      \
      const unsigned short* ksrc_ = kbase + (size_t)(kv0_ + row_) * 64 + sc_;       \
      const unsigned short* vsrc_ = vbase + (size_t)row_ * 2048 + kv0_ + sc_;       \
      __builtin_amdgcn_global_load_lds((const __attribute__((address_space(1))) void*)ksrc_, \
          (__attribute__((address_space(3))) void*)(&Ks[buf_][0] + chunk_*8), 16, 0, 0);     \
      __builtin_amdgcn_global_load_lds((const __attribute__((address_space(1))) void*)vsrc_, \
          (__attribute__((address_space(3))) void*)(&Vs[buf_][0] + chunk_*8), 16, 0, 0);     \
    }                                                                               \
  } while(0)

  STAGE_KV(0, 0);
  for (int t = 0; t < nt; ++t){
    const int cur = t & 1;
    const int kv0 = t * 64;
    if (t + 1 < nt){
      STAGE_KV(t + 1, cur ^ 1);
      asm volatile("s_waitcnt vmcnt(4)" ::: "memory");
    } else {
      asm volatile("s_waitcnt vmcnt(0)" ::: "memory");
    }
    __builtin_amdgcn_s_barrier();
    asm volatile("" ::: "memory");
    const unsigned short* ks = &Ks[cur][0];
    const unsigned short* vs = &Vs[cur][0];

    f32x4 sT[4];
    #pragma unroll
    for (int kf = 0; kf < 4; ++kf){
      const int row = kf*16 + fr;
      const int swr = row & 7;
      short8 k0 = *(const short8*)(ks + row*64 + ((fq ^ swr) << 3));
      short8 k1 = *(const short8*)(ks + row*64 + (((4 + fq) ^ swr) << 3));
      f32x4 s = {0.f, 0.f, 0.f, 0.f};
      s = __builtin_amdgcn_mfma_f32_16x16x32_bf16(k0, aq0, s, 0, 0, 0);
      s = __builtin_amdgcn_mfma_f32_16x16x32_bf16(k1, aq1, s, 0, 0, 0);
      sT[kf] = s;
    }
    if (t == nt - 1){
      #pragma unroll
      for (int kf = 0; kf < 4; ++kf)
        #pragma unroll
        for (int r = 0; r < 4; ++r){
          const int kvcol = kv0 + kf*16 + fq*4 + r;
          if (kvcol > qrow) sT[kf][r] = -1e30f;
        }
    }
    float p[4][4];
    float rs = 0.f;
    #pragma unroll
    for (int kf = 0; kf < 4; ++kf)
      #pragma unroll
      for (int r = 0; r < 4; ++r){
        p[kf][r] = __builtin_amdgcn_exp2f(sT[kf][r] - EXP_BIAS);
        rs += p[kf][r];
      }
    rs += __shfl_xor(rs, 16);
    rs += __shfl_xor(rs, 32);
    lrun += rs;
    unsigned* prow = (unsigned*)&Plds[w][fr][0];
    #pragma unroll
    for (int kf = 0; kf < 4; ++kf)
      #pragma unroll
      for (int jj = 0; jj < 2; ++jj){
        unsigned pk;
        asm("v_cvt_pk_bf16_f32 %0, %1, %2" : "=v"(pk) : "v"(p[kf][2*jj]), "v"(p[kf][2*jj+1]));
        prow[(kf*8 + fq*2 + jj) ^ sw3] = pk;
      }
    asm volatile("s_waitcnt lgkmcnt(0)" ::: "memory");
    const unsigned* crow = (const unsigned*)&Plds[w][fr][0];
    short8 ap0 = *(const short8*)&crow[(fq*4) ^ sw3];
    short8 ap1 = *(const short8*)&crow[(16 + fq*4) ^ sw3];
    __builtin_amdgcn_s_setprio(1);
    #pragma unroll
    for (int dblk = 0; dblk < 4; ++dblk){
      const int d = dblk*16 + fr;
      const int swd = d & 7;
      short8 bv0 = *(const short8*)(vs + d*64 + ((fq ^ swd) << 3));
      short8 bv1 = *(const short8*)(vs + d*64 + (((4 + fq) ^ swd) << 3));
      accO[dblk] = __builtin_amdgcn_mfma_f32_16x16x32_bf16(ap0, bv0, accO[dblk], 0, 0, 0);
      accO[dblk] = __builtin_amdgcn_mfma_f32_16x16x32_bf16(ap1, bv1, accO[dblk], 0, 0, 0);
    }
    __builtin_amdgcn_s_setprio(0);
    asm volatile("" ::: "memory");
    __builtin_amdgcn_s_barrier();
  }
#undef STAGE_KV
  float lq[4];
  #pragma unroll
  for (int r = 0; r < 4; ++r)
    lq[r] = __shfl(lrun, fq*4 + r);
  #pragma unroll
  for (int dblk = 0; dblk < 4; ++dblk)
    #pragma unroll
    for (int r = 0; r < 4; ++r){
      const int s = q0 + fq*4 + r;
      const float o = accO[dblk][r] / lq[r];
      Ob[((size_t)b*2048 + s)*1024 + h*64 + dblk*16 + fr] = f2bf(o);
    }
}

// ---------------- output projection -> fp32 d_out (round-11/12, frozen) ----------------
__global__ __launch_bounds__(256) void gemm_out(
    const unsigned short* __restrict__ Obf, const unsigned short* __restrict__ Wb,
    float* __restrict__ out)
{
  __shared__ __align__(16) unsigned short As[3*4096];
  __shared__ __align__(16) unsigned short Bs[3*2048];
  f32x4 acc[4][2] = {};
  const int tid = threadIdx.x, lane = tid & 63, w = tid >> 6;
  const int wm = w >> 1, wn = w & 1;
  const int fr = lane & 15, fq = lane >> 4;
  const int id  = blockIdx.x;            // 0..511
  const int xcd = id & 7;
  const int lid = id >> 3;               // 0..63
  const int m0 = (xcd*4 + (lid & 3)) * 128;
  const int n0 = (lid >> 2) * 64;
  const int ph = ((fq ^ ((fr + (fr >> 2)) & 3))) * 8;

#define STAGEO(kt, buf) do {                                                        \
    _Pragma("unroll")                                                               \
    for (int i_ = 0; i_ < 2; ++i_){                                                 \
      const int c_ = i_*256 + tid;                                                  \
      const int row_ = c_ >> 2, cd_ = c_ & 3;                                       \
      const int sc_ = ((cd_ ^ ((row_ + (row_ >> 2)) & 3))) << 3;                    \
      const unsigned short* ga_ = Obf + (size_t)(m0 + row_) * 1024 + (kt)*32 + sc_; \
      __builtin_amdgcn_global_load_lds((const __attribute__((address_space(1))) void*)ga_, \
          (__attribute__((address_space(3))) void*)(As + (buf)*4096 + c_*8), 16, 0, 0);    \
    }                                                                               \
    {                                                                               \
      const int c_ = tid;                                                           \
      const int row_ = c_ >> 2, cd_ = c_ & 3;                                       \
      const int sc_ = ((cd_ ^ ((row_ + (row_ >> 2)) & 3))) << 3;                    \
      const unsigned short* gb_ = Wb + (size_t)(n0 + row_) * 1024 + (kt)*32 + sc_;  \
      __builtin_amdgcn_global_load_lds((const __attribute__((address_space(1))) void*)gb_, \
          (__attribute__((address_space(3))) void*)(Bs + (buf)*2048 + c_*8), 16, 0, 0);    \
    }                                                                               \
  } while(0)

  STAGEO(0, 0);
  STAGEO(1, 1);
  for (int t = 0; t < 32; ++t){
    const int cur = t % 3;
    if (t + 2 < 32) STAGEO(t + 2, (t + 2) % 3);
    if (t < 30)       asm volatile("s_waitcnt vmcnt(6)" ::: "memory");
    else if (t == 30) asm volatile("s_waitcnt vmcnt(3)" ::: "memory");
    else              asm volatile("s_waitcnt vmcnt(0)" ::: "memory");
    __builtin_amdgcn_s_barrier();
    asm volatile("" ::: "memory");
    const unsigned short* as = As + cur*4096;
    const unsigned short* bs = Bs + cur*2048;
    short8 af[4], bfv[2];
    #pragma unroll
    for (int mf = 0; mf < 4; ++mf)
      af[mf] = *(const short8*)(as + (wm*64 + mf*16 + fr) * 32 + ph);
    #pragma unroll
    for (int nf = 0; nf < 2; ++nf)
      bfv[nf] = *(const short8*)(bs + (wn*32 + nf*16 + fr) * 32 + ph);
    #pragma unroll
    for (int mf = 0; mf < 4; ++mf)
      #pragma unroll
      for (int nf = 0; nf < 2; ++nf)
        acc[mf][nf] = __builtin_amdgcn_mfma_f32_16x16x32_bf16(af[mf], bfv[nf], acc[mf][nf], 0, 0, 0);
    asm volatile("" ::: "memory");
    __builtin_amdgcn_s_barrier();
  }
#undef STAGEO

  #pragma unroll
  for (int mf = 0; mf < 4; ++mf)
    #pragma unroll
    for (int nf = 0; nf < 2; ++nf){
      const int n = n0 + wn*32 + nf*16 + fr;
      #pragma unroll
      for (int r = 0; r < 4; ++r){
        const int m = m0 + wm*64 + mf*16 + fq*4 + r;
        out[(size_t)m * 1024 + n] = acc[mf][nf][r];
      }
    }
}

extern "C" void kernel_launch(void* const* d_in, const int* in_sizes, int n_in,
                              void* d_out, int out_size, void* d_ws, size_t ws_size,
                              hipStream_t stream) {
  const float* x  = (const float*)d_in[0];
  const int* pos  = (const int*)d_in[1];
  const float* wq = (const float*)d_in[2];
  const float* wk = (const float*)d_in[3];
  const float* wv = (const float*)d_in[4];
  const float* wo = (const float*)d_in[5];
  float* out = (float*)d_out;

  unsigned short* ws = (unsigned short*)d_ws;
  unsigned short* Xb   = ws;                  // 4096x1024
  unsigned short* Wqkv = ws + 4194304UL;      // 3072x1024
  unsigned short* Wo   = ws + 7340032UL;      // 1024x1024
  unsigned short* Qb   = ws + 8388608UL;      // [32][2048][64]
  unsigned short* Kb   = ws + 12582912UL;     // [32][2048][64]
  unsigned short* Vt   = ws + 16777216UL;     // [32][64][2048]
  unsigned short* Ob   = ws + 20971520UL;     // 4096x1024
  float2* tab          = (float2*)(ws + 25165824UL);  // 2048x32 cos/sin (512 KB)

  convert_all<<<4096, 256, 0, stream>>>(x, wq, wk, wv, wo, ws, tab);

  gemm_qkv<<<512, 256, 0, stream>>>(Xb, Wqkv, pos, tab, Qb, Kb, Vt);

  attn_kernel<<<1024, 256, 0, stream>>>(Qb, Kb, Vt, Ob);

  gemm_out<<<512, 256, 0, stream>>>(Ob, Wo, out);
}

// Round 20
// 104.760 us; speedup vs baseline: 1.0694x; 1.0000x over previous
//
#include <hip/hip_runtime.h>
#include <hip/hip_bf16.h>

typedef __attribute__((ext_vector_type(8))) short short8;
typedef __attribute__((ext_vector_type(4))) short short4v;
typedef __attribute__((ext_vector_type(4))) float f32x4;

#define LN10000_DIV32 0.2878231366242558f
#define SCALE_Q_LOG2E 0.18033688011112042f
#define EXP_BIAS 12.0f

__device__ __forceinline__ unsigned short f2bf(float f){
  union { float fv; unsigned u; } a; a.fv = f;
  return (unsigned short)((a.u + 0x7fffu + ((a.u >> 16) & 1u)) >> 16);
}

// ------- convert fp32 -> bf16 (x, W_Q|W_K|W_V, W_O) + RoPE cos/sin table -------
__global__ __launch_bounds__(256) void convert_all(
    const float* __restrict__ x, const float* __restrict__ wq,
    const float* __restrict__ wk, const float* __restrict__ wv,
    const float* __restrict__ wo, unsigned short* __restrict__ dst,
    float2* __restrict__ tab)
{
  size_t t = (size_t)blockIdx.x * 256 + threadIdx.x;
  if (t < 65536UL){
    const int s = (int)(t >> 5), ip = (int)(t & 31);
    float invf = __expf(-(float)ip * LN10000_DIV32);
    float ang = (float)s * invf;
    tab[t] = make_float2(__cosf(ang), __sinf(ang));
  }
  size_t e = t * 8;
  const float* src; size_t off;
  if (e < 4194304UL)      { src = x;  off = e; }
  else if (e < 5242880UL) { src = wq; off = e - 4194304UL; }
  else if (e < 6291456UL) { src = wk; off = e - 5242880UL; }
  else if (e < 7340032UL) { src = wv; off = e - 6291456UL; }
  else                    { src = wo; off = e - 7340032UL; }
  float4 f0 = *(const float4*)(src + off);
  float4 f1 = *(const float4*)(src + off + 4);
  short8 o;
  o[0] = (short)f2bf(f0.x); o[1] = (short)f2bf(f0.y);
  o[2] = (short)f2bf(f0.z); o[3] = (short)f2bf(f0.w);
  o[4] = (short)f2bf(f1.x); o[5] = (short)f2bf(f1.y);
  o[6] = (short)f2bf(f1.z); o[7] = (short)f2bf(f1.w);
  *(short8*)(dst + e) = o;
}

// ---------------- QKV projection: 128x192, BK=64, stage-early + counted vmcnt(10) ----------------
// 512 blocks (2/CU, 80 KB LDS), 256 threads (4 waves, 2M x 2N), per-wave 64x96.
// Per K-tile: {STAGE(t+1) -> vmcnt(10) (tile t's 10 loads done, t+1's stay in flight)
//              -> barrier -> ds_read+MFMA kh0,kh1 -> end barrier}.
// Never drains vmcnt to 0 mid-loop (T4); tile t's loads get a full compute phase of lead.
// Race audit: STAGE(t+1) writes buf[(t+1)&1]; all waves passed iter t-1's END barrier,
// so none still read that buffer. LDS swizzle c ^ (row&7): 0 conflicts (R15-17 verified).
__global__ __launch_bounds__(256, 2) void gemm_qkv(
    const unsigned short* __restrict__ Xb, const unsigned short* __restrict__ Wb,
    const int* __restrict__ positions, const float2* __restrict__ tab,
    unsigned short* __restrict__ Qb, unsigned short* __restrict__ Kb,
    unsigned short* __restrict__ Vtb)
{
  __shared__ __align__(16) unsigned short As[2*8192];   // 2 x 128x64 (32 KB)
  __shared__ __align__(16) unsigned short Bs[2*12288];  // 2 x 192x64 (48 KB)
  f32x4 acc[4][6] = {};
  const int tid = threadIdx.x, lane = tid & 63, w = tid >> 6;
  const int wm = w >> 1, wn = w & 1;
  const int fr = lane & 15, fq = lane >> 4;
  const int id  = blockIdx.x;                           // 0..511
  const int xcd = id & 7;
  const int lid = id >> 3;                              // 0..63
  const int m0 = (lid & 31) * 128;
  const int n0 = (xcd*2 + (lid >> 5)) * 192;

#define STAGE_ALL(kt, buf) do {                                                     \
    _Pragma("unroll")                                                               \
    for (int i_ = 0; i_ < 4; ++i_){                    /* A: 1024 chunks */         \
      const int c_ = i_*256 + tid;                                                  \
      const int row_ = c_ >> 3, cd_ = c_ & 7;                                       \
      const int sc_ = (cd_ ^ (row_ & 7)) << 3;                                      \
      const unsigned short* ga_ = Xb + (size_t)(m0 + row_) * 1024 + (kt)*64 + sc_;  \
      __builtin_amdgcn_global_load_lds((const __attribute__((address_space(1))) void*)ga_, \
          (__attribute__((address_space(3))) void*)(As + (buf)*8192 + c_*8), 16, 0, 0);    \
    }                                                                               \
    _Pragma("unroll")                                                               \
    for (int i_ = 0; i_ < 6; ++i_){                    /* B: 1536 chunks */         \
      const int c_ = i_*256 + tid;                                                  \
      const int row_ = c_ >> 3, cd_ = c_ & 7;                                       \
      const int sc_ = (cd_ ^ (row_ & 7)) << 3;                                      \
      const unsigned short* gb_ = Wb + (size_t)(n0 + row_) * 1024 + (kt)*64 + sc_;  \
      __builtin_amdgcn_global_load_lds((const __attribute__((address_space(1))) void*)gb_, \
          (__attribute__((address_space(3))) void*)(Bs + (buf)*12288 + c_*8), 16, 0, 0);   \
    }                                                                               \
  } while(0)

  STAGE_ALL(0, 0);                       // prologue: tile 0

  const int row_a0 = wm*64 + fr;
  const int row_b0 = wn*96 + fr;

  for (int t = 0; t < 16; ++t){
    const int cur = t & 1;
    if (t + 1 < 16){
      STAGE_ALL(t + 1, cur ^ 1);         // safe: end-barrier of iter t-1 passed
      asm volatile("s_waitcnt vmcnt(10)" ::: "memory");  // tile t's 10 loads done
    } else {
      asm volatile("s_waitcnt vmcnt(0)" ::: "memory");
    }
    __builtin_amdgcn_s_barrier();        // tile t visible to all waves
    asm volatile("" ::: "memory");
    const unsigned short* as = As + cur*8192;
    const unsigned short* bs = Bs + cur*12288;
    short8 af[4], bfv[6];

#define LDA(mf_, kh_) do { \
      const int row_ = row_a0 + (mf_)*16; \
      const int c_ = ((kh_)*4 + fq) ^ (row_ & 7); \
      af[mf_] = *(const short8*)(as + row_*64 + c_*8); } while(0)
#define LDB(nf_, kh_) do { \
      const int row_ = row_b0 + (nf_)*16; \
      const int c_ = ((kh_)*4 + fq) ^ (row_ & 7); \
      bfv[nf_] = *(const short8*)(bs + row_*64 + c_*8); } while(0)

    // ---- k-half 0 ----
    LDA(0,0); LDA(1,0); LDA(2,0); LDA(3,0);
    LDB(0,0); LDB(1,0); LDB(2,0); LDB(3,0); LDB(4,0); LDB(5,0);
    __builtin_amdgcn_s_setprio(1);
    #pragma unroll
    for (int mf = 0; mf < 4; ++mf)
      #pragma unroll
      for (int nf = 0; nf < 6; ++nf)
        acc[mf][nf] = __builtin_amdgcn_mfma_f32_16x16x32_bf16(af[mf], bfv[nf], acc[mf][nf], 0, 0, 0);
    __builtin_amdgcn_s_setprio(0);

    // ---- k-half 1 ----
    LDA(0,1); LDA(1,1); LDA(2,1); LDA(3,1);
    LDB(0,1); LDB(1,1); LDB(2,1); LDB(3,1); LDB(4,1); LDB(5,1);
    __builtin_amdgcn_s_setprio(1);
    #pragma unroll
    for (int mf = 0; mf < 4; ++mf)
      #pragma unroll
      for (int nf = 0; nf < 6; ++nf)
        acc[mf][nf] = __builtin_amdgcn_mfma_f32_16x16x32_bf16(af[mf], bfv[nf], acc[mf][nf], 0, 0, 0);
    __builtin_amdgcn_s_setprio(0);
    asm volatile("" ::: "memory");
    __builtin_amdgcn_s_barrier();        // end barrier: buf[cur] reusable next iter
  }
#undef STAGE_ALL

  // ---- epilogue: table-RoPE + scatter; V stores packed as short4 (proven) ----
  #pragma unroll
  for (int mf = 0; mf < 4; ++mf){
    int pm[4];
    #pragma unroll
    for (int r = 0; r < 4; ++r){
      const int m = m0 + wm*64 + mf*16 + fq*4 + r;
      pm[r] = positions[m] & 2047;
    }
    const int mbase = m0 + wm*64 + mf*16 + fq*4;
    const int b = mbase >> 11;
    const int s0 = mbase & 2047;
    #pragma unroll
    for (int nf = 0; nf < 6; ++nf){
      const int n = n0 + wn*96 + nf*16 + fr;
      const int seg = n >> 10;
      const int h = (n & 1023) >> 6, d = n & 63;
      const size_t bh = (size_t)b * 16 + h;
      if (seg == 2){
        short4v pack;
        #pragma unroll
        for (int r = 0; r < 4; ++r)
          pack[r] = (short)f2bf(acc[mf][nf][r]);
        *(short4v*)&Vtb[(bh*64 + d)*2048 + s0] = pack;
      } else {
        const int ip = d >> 1;
        #pragma unroll
        for (int r = 0; r < 4; ++r){
          float v = acc[mf][nf][r];
          float pv = __shfl_xor(v, 1);
          const float2 cs = tab[(pm[r] << 5) + ip];
          float outv = (d & 1) ? (cs.x * v + cs.y * pv)
                               : (cs.x * v - cs.y * pv);
          if (seg == 0) outv *= SCALE_Q_LOG2E;
          const unsigned short ob = f2bf(outv);
          const int s = s0 + r;
          if (seg == 0) Qb[(bh*2048 + s)*64 + d] = ob;
          else          Kb[(bh*2048 + s)*64 + d] = ob;
        }
      }
    }
  }
}

// ---------------- causal flash attention v6: fixed-bias softmax (frozen) ----------------
__global__ __launch_bounds__(256) void attn_kernel(
    const unsigned short* __restrict__ Qb, const unsigned short* __restrict__ Kb,
    const unsigned short* __restrict__ Vtb, unsigned short* __restrict__ Ob)
{
  __shared__ __align__(16) unsigned short Ks[2][4096];
  __shared__ __align__(16) unsigned short Vs[2][4096];
  __shared__ __align__(16) unsigned short Plds[4][16][64];

  const int tid = threadIdx.x, lane = tid & 63, w = tid >> 6;
  const int fr = lane & 15, fq = lane >> 4;

  const int i = blockIdx.x;
  const int bh = (i & 7) | (((i >> 3) & 3) << 3);   // XCD-pinned
  const int tile = 31 - (i >> 5);                   // longest tiles first
  const int b = bh >> 4, h = bh & 15;
  const int q0 = tile * 64 + w * 16;
  const size_t qk_base = (size_t)bh * 2048 * 64;
  const unsigned short* kbase = Kb + qk_base;
  const unsigned short* vbase = Vtb + (size_t)bh * 64 * 2048;

  const unsigned short* qp = Qb + qk_base + (size_t)(q0 + fr) * 64 + fq * 8;
  short8 aq0 = *(const short8*)qp;
  short8 aq1 = *(const short8*)(qp + 32);

  f32x4 accO[4] = {};
  float lrun = 0.f;
  const int qrow = q0 + fr;
  const int nt = tile + 1;
  const int sw3 = (fr & 7) << 2;

#define STAGE_KV(t_, buf_) do {                                                     \
    const int kv0_ = (t_) * 64;                                                     \
    _Pragma("unroll")                                                               \
    for (int ii_ = 0; ii_ < 2; ++ii_){                                              \
      const int chunk_ = ii_ * 256 + tid;                                           \
      const int row_ = chunk_ >> 3, cd_ = chunk_ & 7;                               \
      const int sc_ = (cd_ ^ (row_ & 7)) << 3;                                      \
      const unsigned short* ksrc_ = kbase + (size_t)(kv0_ + row_) * 64 + sc_;       \
      const unsigned short* vsrc_ = vbase + (size_t)row_ * 2048 + kv0_ + sc_;       \
      __builtin_amdgcn_global_load_lds((const __attribute__((address_space(1))) void*)ksrc_, \
          (__attribute__((address_space(3))) void*)(&Ks[buf_][0] + chunk_*8), 16, 0, 0);     \
      __builtin_amdgcn_global_load_lds((const __attribute__((address_space(1))) void*)vsrc_, \
          (__attribute__((address_space(3))) void*)(&Vs[buf_][0] + chunk_*8), 16, 0, 0);     \
    }                                                                               \
  } while(0)

  STAGE_KV(0, 0);
  for (int t = 0; t < nt; ++t){
    const int cur = t & 1;
    const int kv0 = t * 64;
    if (t + 1 < nt){
      STAGE_KV(t + 1, cur ^ 1);
      asm volatile("s_waitcnt vmcnt(4)" ::: "memory");
    } else {
      asm volatile("s_waitcnt vmcnt(0)" ::: "memory");
    }
    __builtin_amdgcn_s_barrier();
    asm volatile("" ::: "memory");
    const unsigned short* ks = &Ks[cur][0];
    const unsigned short* vs = &Vs[cur][0];

    f32x4 sT[4];
    #pragma unroll
    for (int kf = 0; kf < 4; ++kf){
      const int row = kf*16 + fr;
      const int swr = row & 7;
      short8 k0 = *(const short8*)(ks + row*64 + ((fq ^ swr) << 3));
      short8 k1 = *(const short8*)(ks + row*64 + (((4 + fq) ^ swr) << 3));
      f32x4 s = {0.f, 0.f, 0.f, 0.f};
      s = __builtin_amdgcn_mfma_f32_16x16x32_bf16(k0, aq0, s, 0, 0, 0);
      s = __builtin_amdgcn_mfma_f32_16x16x32_bf16(k1, aq1, s, 0, 0, 0);
      sT[kf] = s;
    }
    if (t == nt - 1){
      #pragma unroll
      for (int kf = 0; kf < 4; ++kf)
        #pragma unroll
        for (int r = 0; r < 4; ++r){
          const int kvcol = kv0 + kf*16 + fq*4 + r;
          if (kvcol > qrow) sT[kf][r] = -1e30f;
        }
    }
    float p[4][4];
    float rs = 0.f;
    #pragma unroll
    for (int kf = 0; kf < 4; ++kf)
      #pragma unroll
      for (int r = 0; r < 4; ++r){
        p[kf][r] = __builtin_amdgcn_exp2f(sT[kf][r] - EXP_BIAS);
        rs += p[kf][r];
      }
    rs += __shfl_xor(rs, 16);
    rs += __shfl_xor(rs, 32);
    lrun += rs;
    unsigned* prow = (unsigned*)&Plds[w][fr][0];
    #pragma unroll
    for (int kf = 0; kf < 4; ++kf)
      #pragma unroll
      for (int jj = 0; jj < 2; ++jj){
        unsigned pk;
        asm("v_cvt_pk_bf16_f32 %0, %1, %2" : "=v"(pk) : "v"(p[kf][2*jj]), "v"(p[kf][2*jj+1]));
        prow[(kf*8 + fq*2 + jj) ^ sw3] = pk;
      }
    asm volatile("s_waitcnt lgkmcnt(0)" ::: "memory");
    const unsigned* crow = (const unsigned*)&Plds[w][fr][0];
    short8 ap0 = *(const short8*)&crow[(fq*4) ^ sw3];
    short8 ap1 = *(const short8*)&crow[(16 + fq*4) ^ sw3];
    __builtin_amdgcn_s_setprio(1);
    #pragma unroll
    for (int dblk = 0; dblk < 4; ++dblk){
      const int d = dblk*16 + fr;
      const int swd = d & 7;
      short8 bv0 = *(const short8*)(vs + d*64 + ((fq ^ swd) << 3));
      short8 bv1 = *(const short8*)(vs + d*64 + (((4 + fq) ^ swd) << 3));
      accO[dblk] = __builtin_amdgcn_mfma_f32_16x16x32_bf16(ap0, bv0, accO[dblk], 0, 0, 0);
      accO[dblk] = __builtin_amdgcn_mfma_f32_16x16x32_bf16(ap1, bv1, accO[dblk], 0, 0, 0);
    }
    __builtin_amdgcn_s_setprio(0);
    asm volatile("" ::: "memory");
    __builtin_amdgcn_s_barrier();
  }
#undef STAGE_KV
  float lq[4];
  #pragma unroll
  for (int r = 0; r < 4; ++r)
    lq[r] = __shfl(lrun, fq*4 + r);
  #pragma unroll
  for (int dblk = 0; dblk < 4; ++dblk)
    #pragma unroll
    for (int r = 0; r < 4; ++r){
      const int s = q0 + fq*4 + r;
      const float o = accO[dblk][r] / lq[r];
      Ob[((size_t)b*2048 + s)*1024 + h*64 + dblk*16 + fr] = f2bf(o);
    }
}

// ---------------- output projection -> fp32 d_out (frozen) ----------------
__global__ __launch_bounds__(256) void gemm_out(
    const unsigned short* __restrict__ Obf, const unsigned short* __restrict__ Wb,
    float* __restrict__ out)
{
  __shared__ __align__(16) unsigned short As[3*4096];
  __shared__ __align__(16) unsigned short Bs[3*2048];
  f32x4 acc[4][2] = {};
  const int tid = threadIdx.x, lane = tid & 63, w = tid >> 6;
  const int wm = w >> 1, wn = w & 1;
  const int fr = lane & 15, fq = lane >> 4;
  const int id  = blockIdx.x;            // 0..511
  const int xcd = id & 7;
  const int lid = id >> 3;               // 0..63
  const int m0 = (xcd*4 + (lid & 3)) * 128;
  const int n0 = (lid >> 2) * 64;
  const int ph = ((fq ^ ((fr + (fr >> 2)) & 3))) * 8;

#define STAGEO(kt, buf) do {                                                        \
    _Pragma("unroll")                                                               \
    for (int i_ = 0; i_ < 2; ++i_){                                                 \
      const int c_ = i_*256 + tid;                                                  \
      const int row_ = c_ >> 2, cd_ = c_ & 3;                                       \
      const int sc_ = ((cd_ ^ ((row_ + (row_ >> 2)) & 3))) << 3;                    \
      const unsigned short* ga_ = Obf + (size_t)(m0 + row_) * 1024 + (kt)*32 + sc_; \
      __builtin_amdgcn_global_load_lds((const __attribute__((address_space(1))) void*)ga_, \
          (__attribute__((address_space(3))) void*)(As + (buf)*4096 + c_*8), 16, 0, 0);    \
    }                                                                               \
    {                                                                               \
      const int c_ = tid;                                                           \
      const int row_ = c_ >> 2, cd_ = c_ & 3;                                       \
      const int sc_ = ((cd_ ^ ((row_ + (row_ >> 2)) & 3))) << 3;                    \
      const unsigned short* gb_ = Wb + (size_t)(n0 + row_) * 1024 + (kt)*32 + sc_;  \
      __builtin_amdgcn_global_load_lds((const __attribute__((address_space(1))) void*)gb_, \
          (__attribute__((address_space(3))) void*)(Bs + (buf)*2048 + c_*8), 16, 0, 0);    \
    }                                                                               \
  } while(0)

  STAGEO(0, 0);
  STAGEO(1, 1);
  for (int t = 0; t < 32; ++t){
    const int cur = t % 3;
    if (t + 2 < 32) STAGEO(t + 2, (t + 2) % 3);
    if (t < 30)       asm volatile("s_waitcnt vmcnt(6)" ::: "memory");
    else if (t == 30) asm volatile("s_waitcnt vmcnt(3)" ::: "memory");
    else              asm volatile("s_waitcnt vmcnt(0)" ::: "memory");
    __builtin_amdgcn_s_barrier();
    asm volatile("" ::: "memory");
    const unsigned short* as = As + cur*4096;
    const unsigned short* bs = Bs + cur*2048;
    short8 af[4], bfv[2];
    #pragma unroll
    for (int mf = 0; mf < 4; ++mf)
      af[mf] = *(const short8*)(as + (wm*64 + mf*16 + fr) * 32 + ph);
    #pragma unroll
    for (int nf = 0; nf < 2; ++nf)
      bfv[nf] = *(const short8*)(bs + (wn*32 + nf*16 + fr) * 32 + ph);
    #pragma unroll
    for (int mf = 0; mf < 4; ++mf)
      #pragma unroll
      for (int nf = 0; nf < 2; ++nf)
        acc[mf][nf] = __builtin_amdgcn_mfma_f32_16x16x32_bf16(af[mf], bfv[nf], acc[mf][nf], 0, 0, 0);
    asm volatile("" ::: "memory");
    __builtin_amdgcn_s_barrier();
  }
#undef STAGEO

  #pragma unroll
  for (int mf = 0; mf < 4; ++mf)
    #pragma unroll
    for (int nf = 0; nf < 2; ++nf){
      const int n = n0 + wn*32 + nf*16 + fr;
      #pragma unroll
      for (int r = 0; r < 4; ++r){
        const int m = m0 + wm*64 + mf*16 + fq*4 + r;
        out[(size_t)m * 1024 + n] = acc[mf][nf][r];
      }
    }
}

extern "C" void kernel_launch(void* const* d_in, const int* in_sizes, int n_in,
                              void* d_out, int out_size, void* d_ws, size_t ws_size,
                              hipStream_t stream) {
  const float* x  = (const float*)d_in[0];
  const int* pos  = (const int*)d_in[1];
  const float* wq = (const float*)d_in[2];
  const float* wk = (const float*)d_in[3];
  const float* wv = (const float*)d_in[4];
  const float* wo = (const float*)d_in[5];
  float* out = (float*)d_out;

  unsigned short* ws = (unsigned short*)d_ws;
  unsigned short* Xb   = ws;                  // 4096x1024
  unsigned short* Wqkv = ws + 4194304UL;      // 3072x1024
  unsigned short* Wo   = ws + 7340032UL;      // 1024x1024
  unsigned short* Qb   = ws + 8388608UL;      // [32][2048][64]
  unsigned short* Kb   = ws + 12582912UL;     // [32][2048][64]
  unsigned short* Vt   = ws + 16777216UL;     // [32][64][2048]
  unsigned short* Ob   = ws + 20971520UL;     // 4096x1024
  float2* tab          = (float2*)(ws + 25165824UL);  // 2048x32 cos/sin (512 KB)

  convert_all<<<4096, 256, 0, stream>>>(x, wq, wk, wv, wo, ws, tab);

  gemm_qkv<<<512, 256, 0, stream>>>(Xb, Wqkv, pos, tab, Qb, Kb, Vt);

  attn_kernel<<<1024, 256, 0, stream>>>(Qb, Kb, Vt, Ob);

  gemm_out<<<512, 256, 0, stream>>>(Ob, Wo, out);
}

// Round 21
// 103.363 us; speedup vs baseline: 1.0838x; 1.0135x over previous
//
#include <hip/hip_runtime.h>
#include <hip/hip_bf16.h>

typedef __attribute__((ext_vector_type(8))) short short8;
typedef __attribute__((ext_vector_type(4))) short short4v;
typedef __attribute__((ext_vector_type(4))) float f32x4;

#define LN10000_DIV32 0.2878231366242558f
#define SCALE_Q_LOG2E 0.18033688011112042f
#define EXP_BIAS 12.0f

__device__ __forceinline__ unsigned short f2bf(float f){
  union { float fv; unsigned u; } a; a.fv = f;
  return (unsigned short)((a.u + 0x7fffu + ((a.u >> 16) & 1u)) >> 16);
}

// ------- convert fp32 -> bf16 (x, W_Q|W_K|W_V, W_O) + RoPE cos/sin table -------
__global__ __launch_bounds__(256) void convert_all(
    const float* __restrict__ x, const float* __restrict__ wq,
    const float* __restrict__ wk, const float* __restrict__ wv,
    const float* __restrict__ wo, unsigned short* __restrict__ dst,
    float2* __restrict__ tab)
{
  size_t t = (size_t)blockIdx.x * 256 + threadIdx.x;
  if (t < 65536UL){
    const int s = (int)(t >> 5), ip = (int)(t & 31);
    float invf = __expf(-(float)ip * LN10000_DIV32);
    float ang = (float)s * invf;
    tab[t] = make_float2(__cosf(ang), __sinf(ang));
  }
  size_t e = t * 8;
  const float* src; size_t off;
  if (e < 4194304UL)      { src = x;  off = e; }
  else if (e < 5242880UL) { src = wq; off = e - 4194304UL; }
  else if (e < 6291456UL) { src = wk; off = e - 5242880UL; }
  else if (e < 7340032UL) { src = wv; off = e - 6291456UL; }
  else                    { src = wo; off = e - 7340032UL; }
  float4 f0 = *(const float4*)(src + off);
  float4 f1 = *(const float4*)(src + off + 4);
  short8 o;
  o[0] = (short)f2bf(f0.x); o[1] = (short)f2bf(f0.y);
  o[2] = (short)f2bf(f0.z); o[3] = (short)f2bf(f0.w);
  o[4] = (short)f2bf(f1.x); o[5] = (short)f2bf(f1.y);
  o[6] = (short)f2bf(f1.z); o[7] = (short)f2bf(f1.w);
  *(short8*)(dst + e) = o;
}

// ---------------- QKV projection: 128x192, BK=64, 8 waves (2Mx4N), 16 waves/CU ----------------
// 512 blocks (2/CU by 80 KB LDS), 512 threads. Per-wave 64x48 (acc[4][3]).
// Same stage-early + counted vmcnt(5) skeleton as R20 (never 0 mid-loop).
// Doubles waves/SIMD 2->4 vs the 256-thread variant -- the occupancy lever that has
// tracked every GEMM delta this session. LDS swizzle c ^ (row&7): 0 conflicts.
__global__ __launch_bounds__(512, 2) void gemm_qkv(
    const unsigned short* __restrict__ Xb, const unsigned short* __restrict__ Wb,
    const int* __restrict__ positions, const float2* __restrict__ tab,
    unsigned short* __restrict__ Qb, unsigned short* __restrict__ Kb,
    unsigned short* __restrict__ Vtb)
{
  __shared__ __align__(16) unsigned short As[2*8192];   // 2 x 128x64 (32 KB)
  __shared__ __align__(16) unsigned short Bs[2*12288];  // 2 x 192x64 (48 KB)
  f32x4 acc[4][3] = {};
  const int tid = threadIdx.x, lane = tid & 63, w = tid >> 6;
  const int wm = w >> 2, wn = w & 3;                    // 2 M-groups x 4 N-groups
  const int fr = lane & 15, fq = lane >> 4;
  const int id  = blockIdx.x;                           // 0..511
  const int xcd = id & 7;
  const int lid = id >> 3;                              // 0..63
  const int m0 = (lid & 31) * 128;
  const int n0 = (xcd*2 + (lid >> 5)) * 192;

#define STAGE_ALL(kt, buf) do {                                                     \
    _Pragma("unroll")                                                               \
    for (int i_ = 0; i_ < 2; ++i_){                    /* A: 1024 chunks */         \
      const int c_ = i_*512 + tid;                                                  \
      const int row_ = c_ >> 3, cd_ = c_ & 7;                                       \
      const int sc_ = (cd_ ^ (row_ & 7)) << 3;                                      \
      const unsigned short* ga_ = Xb + (size_t)(m0 + row_) * 1024 + (kt)*64 + sc_;  \
      __builtin_amdgcn_global_load_lds((const __attribute__((address_space(1))) void*)ga_, \
          (__attribute__((address_space(3))) void*)(As + (buf)*8192 + c_*8), 16, 0, 0);    \
    }                                                                               \
    _Pragma("unroll")                                                               \
    for (int i_ = 0; i_ < 3; ++i_){                    /* B: 1536 chunks */         \
      const int c_ = i_*512 + tid;                                                  \
      const int row_ = c_ >> 3, cd_ = c_ & 7;                                       \
      const int sc_ = (cd_ ^ (row_ & 7)) << 3;                                      \
      const unsigned short* gb_ = Wb + (size_t)(n0 + row_) * 1024 + (kt)*64 + sc_;  \
      __builtin_amdgcn_global_load_lds((const __attribute__((address_space(1))) void*)gb_, \
          (__attribute__((address_space(3))) void*)(Bs + (buf)*12288 + c_*8), 16, 0, 0);   \
    }                                                                               \
  } while(0)

  STAGE_ALL(0, 0);                       // prologue: tile 0

  const int row_a0 = wm*64 + fr;
  const int row_b0 = wn*48 + fr;

  for (int t = 0; t < 16; ++t){
    const int cur = t & 1;
    if (t + 1 < 16){
      STAGE_ALL(t + 1, cur ^ 1);         // safe: end-barrier of iter t-1 passed
      asm volatile("s_waitcnt vmcnt(5)" ::: "memory");   // tile t's 5 loads done
    } else {
      asm volatile("s_waitcnt vmcnt(0)" ::: "memory");
    }
    __builtin_amdgcn_s_barrier();        // tile t visible to all waves
    asm volatile("" ::: "memory");
    const unsigned short* as = As + cur*8192;
    const unsigned short* bs = Bs + cur*12288;
    short8 af[4], bfv[3];

#define LDA(mf_, kh_) do { \
      const int row_ = row_a0 + (mf_)*16; \
      const int c_ = ((kh_)*4 + fq) ^ (row_ & 7); \
      af[mf_] = *(const short8*)(as + row_*64 + c_*8); } while(0)
#define LDB(nf_, kh_) do { \
      const int row_ = row_b0 + (nf_)*16; \
      const int c_ = ((kh_)*4 + fq) ^ (row_ & 7); \
      bfv[nf_] = *(const short8*)(bs + row_*64 + c_*8); } while(0)

    // ---- k-half 0 ----
    LDA(0,0); LDA(1,0); LDA(2,0); LDA(3,0);
    LDB(0,0); LDB(1,0); LDB(2,0);
    __builtin_amdgcn_s_setprio(1);
    #pragma unroll
    for (int mf = 0; mf < 4; ++mf)
      #pragma unroll
      for (int nf = 0; nf < 3; ++nf)
        acc[mf][nf] = __builtin_amdgcn_mfma_f32_16x16x32_bf16(af[mf], bfv[nf], acc[mf][nf], 0, 0, 0);
    __builtin_amdgcn_s_setprio(0);

    // ---- k-half 1 ----
    LDA(0,1); LDA(1,1); LDA(2,1); LDA(3,1);
    LDB(0,1); LDB(1,1); LDB(2,1);
    __builtin_amdgcn_s_setprio(1);
    #pragma unroll
    for (int mf = 0; mf < 4; ++mf)
      #pragma unroll
      for (int nf = 0; nf < 3; ++nf)
        acc[mf][nf] = __builtin_amdgcn_mfma_f32_16x16x32_bf16(af[mf], bfv[nf], acc[mf][nf], 0, 0, 0);
    __builtin_amdgcn_s_setprio(0);
    asm volatile("" ::: "memory");
    __builtin_amdgcn_s_barrier();        // end barrier: buf[cur] reusable next iter
  }
#undef STAGE_ALL

  // ---- epilogue: table-RoPE + scatter; V stores packed as short4 ----
  #pragma unroll
  for (int mf = 0; mf < 4; ++mf){
    int pm[4];
    #pragma unroll
    for (int r = 0; r < 4; ++r){
      const int m = m0 + wm*64 + mf*16 + fq*4 + r;
      pm[r] = positions[m] & 2047;
    }
    const int mbase = m0 + wm*64 + mf*16 + fq*4;
    const int b = mbase >> 11;
    const int s0 = mbase & 2047;
    #pragma unroll
    for (int nf = 0; nf < 3; ++nf){
      const int n = n0 + wn*48 + nf*16 + fr;
      const int seg = n >> 10;               // uniform per 16-wide fragment
      const int h = (n & 1023) >> 6, d = n & 63;
      const size_t bh = (size_t)b * 16 + h;
      if (seg == 2){
        short4v pack;
        #pragma unroll
        for (int r = 0; r < 4; ++r)
          pack[r] = (short)f2bf(acc[mf][nf][r]);
        *(short4v*)&Vtb[(bh*64 + d)*2048 + s0] = pack;
      } else {
        const int ip = d >> 1;
        #pragma unroll
        for (int r = 0; r < 4; ++r){
          float v = acc[mf][nf][r];
          float pv = __shfl_xor(v, 1);
          const float2 cs = tab[(pm[r] << 5) + ip];
          float outv = (d & 1) ? (cs.x * v + cs.y * pv)
                               : (cs.x * v - cs.y * pv);
          if (seg == 0) outv *= SCALE_Q_LOG2E;
          const unsigned short ob = f2bf(outv);
          const int s = s0 + r;
          if (seg == 0) Qb[(bh*2048 + s)*64 + d] = ob;
          else          Kb[(bh*2048 + s)*64 + d] = ob;
        }
      }
    }
  }
}

// ---------------- causal flash attention v6: fixed-bias softmax (frozen) ----------------
__global__ __launch_bounds__(256) void attn_kernel(
    const unsigned short* __restrict__ Qb, const unsigned short* __restrict__ Kb,
    const unsigned short* __restrict__ Vtb, unsigned short* __restrict__ Ob)
{
  __shared__ __align__(16) unsigned short Ks[2][4096];
  __shared__ __align__(16) unsigned short Vs[2][4096];
  __shared__ __align__(16) unsigned short Plds[4][16][64];

  const int tid = threadIdx.x, lane = tid & 63, w = tid >> 6;
  const int fr = lane & 15, fq = lane >> 4;

  const int i = blockIdx.x;
  const int bh = (i & 7) | (((i >> 3) & 3) << 3);   // XCD-pinned
  const int tile = 31 - (i >> 5);                   // longest tiles first
  const int b = bh >> 4, h = bh & 15;
  const int q0 = tile * 64 + w * 16;
  const size_t qk_base = (size_t)bh * 2048 * 64;
  const unsigned short* kbase = Kb + qk_base;
  const unsigned short* vbase = Vtb + (size_t)bh * 64 * 2048;

  const unsigned short* qp = Qb + qk_base + (size_t)(q0 + fr) * 64 + fq * 8;
  short8 aq0 = *(const short8*)qp;
  short8 aq1 = *(const short8*)(qp + 32);

  f32x4 accO[4] = {};
  float lrun = 0.f;
  const int qrow = q0 + fr;
  const int nt = tile + 1;
  const int sw3 = (fr & 7) << 2;

#define STAGE_KV(t_, buf_) do {                                                     \
    const int kv0_ = (t_) * 64;                                                     \
    _Pragma("unroll")                                                               \
    for (int ii_ = 0; ii_ < 2; ++ii_){                                              \
      const int chunk_ = ii_ * 256 + tid;                                           \
      const int row_ = chunk_ >> 3, cd_ = chunk_ & 7;                               \
      const int sc_ = (cd_ ^ (row_ & 7)) << 3;                                      \
      const unsigned short* ksrc_ = kbase + (size_t)(kv0_ + row_) * 64 + sc_;       \
      const unsigned short* vsrc_ = vbase + (size_t)row_ * 2048 + kv0_ + sc_;       \
      __builtin_amdgcn_global_load_lds((const __attribute__((address_space(1))) void*)ksrc_, \
          (__attribute__((address_space(3))) void*)(&Ks[buf_][0] + chunk_*8), 16, 0, 0);     \
      __builtin_amdgcn_global_load_lds((const __attribute__((address_space(1))) void*)vsrc_, \
          (__attribute__((address_space(3))) void*)(&Vs[buf_][0] + chunk_*8), 16, 0, 0);     \
    }                                                                               \
  } while(0)

  STAGE_KV(0, 0);
  for (int t = 0; t < nt; ++t){
    const int cur = t & 1;
    const int kv0 = t * 64;
    if (t + 1 < nt){
      STAGE_KV(t + 1, cur ^ 1);
      asm volatile("s_waitcnt vmcnt(4)" ::: "memory");
    } else {
      asm volatile("s_waitcnt vmcnt(0)" ::: "memory");
    }
    __builtin_amdgcn_s_barrier();
    asm volatile("" ::: "memory");
    const unsigned short* ks = &Ks[cur][0];
    const unsigned short* vs = &Vs[cur][0];

    f32x4 sT[4];
    #pragma unroll
    for (int kf = 0; kf < 4; ++kf){
      const int row = kf*16 + fr;
      const int swr = row & 7;
      short8 k0 = *(const short8*)(ks + row*64 + ((fq ^ swr) << 3));
      short8 k1 = *(const short8*)(ks + row*64 + (((4 + fq) ^ swr) << 3));
      f32x4 s = {0.f, 0.f, 0.f, 0.f};
      s = __builtin_amdgcn_mfma_f32_16x16x32_bf16(k0, aq0, s, 0, 0, 0);
      s = __builtin_amdgcn_mfma_f32_16x16x32_bf16(k1, aq1, s, 0, 0, 0);
      sT[kf] = s;
    }
    if (t == nt - 1){
      #pragma unroll
      for (int kf = 0; kf < 4; ++kf)
        #pragma unroll
        for (int r = 0; r < 4; ++r){
          const int kvcol = kv0 + kf*16 + fq*4 + r;
          if (kvcol > qrow) sT[kf][r] = -1e30f;
        }
    }
    float p[4][4];
    float rs = 0.f;
    #pragma unroll
    for (int kf = 0; kf < 4; ++kf)
      #pragma unroll
      for (int r = 0; r < 4; ++r){
        p[kf][r] = __builtin_amdgcn_exp2f(sT[kf][r] - EXP_BIAS);
        rs += p[kf][r];
      }
    rs += __shfl_xor(rs, 16);
    rs += __shfl_xor(rs, 32);
    lrun += rs;
    unsigned* prow = (unsigned*)&Plds[w][fr][0];
    #pragma unroll
    for (int kf = 0; kf < 4; ++kf)
      #pragma unroll
      for (int jj = 0; jj < 2; ++jj){
        unsigned pk;
        asm("v_cvt_pk_bf16_f32 %0, %1, %2" : "=v"(pk) : "v"(p[kf][2*jj]), "v"(p[kf][2*jj+1]));
        prow[(kf*8 + fq*2 + jj) ^ sw3] = pk;
      }
    asm volatile("s_waitcnt lgkmcnt(0)" ::: "memory");
    const unsigned* crow = (const unsigned*)&Plds[w][fr][0];
    short8 ap0 = *(const short8*)&crow[(fq*4) ^ sw3];
    short8 ap1 = *(const short8*)&crow[(16 + fq*4) ^ sw3];
    __builtin_amdgcn_s_setprio(1);
    #pragma unroll
    for (int dblk = 0; dblk < 4; ++dblk){
      const int d = dblk*16 + fr;
      const int swd = d & 7;
      short8 bv0 = *(const short8*)(vs + d*64 + ((fq ^ swd) << 3));
      short8 bv1 = *(const short8*)(vs + d*64 + (((4 + fq) ^ swd) << 3));
      accO[dblk] = __builtin_amdgcn_mfma_f32_16x16x32_bf16(ap0, bv0, accO[dblk], 0, 0, 0);
      accO[dblk] = __builtin_amdgcn_mfma_f32_16x16x32_bf16(ap1, bv1, accO[dblk], 0, 0, 0);
    }
    __builtin_amdgcn_s_setprio(0);
    asm volatile("" ::: "memory");
    __builtin_amdgcn_s_barrier();
  }
#undef STAGE_KV
  float lq[4];
  #pragma unroll
  for (int r = 0; r < 4; ++r)
    lq[r] = __shfl(lrun, fq*4 + r);
  #pragma unroll
  for (int dblk = 0; dblk < 4; ++dblk)
    #pragma unroll
    for (int r = 0; r < 4; ++r){
      const int s = q0 + fq*4 + r;
      const float o = accO[dblk][r] / lq[r];
      Ob[((size_t)b*2048 + s)*1024 + h*64 + dblk*16 + fr] = f2bf(o);
    }
}

// ---------------- output projection -> fp32 d_out (frozen) ----------------
__global__ __launch_bounds__(256) void gemm_out(
    const unsigned short* __restrict__ Obf, const unsigned short* __restrict__ Wb,
    float* __restrict__ out)
{
  __shared__ __align__(16) unsigned short As[3*4096];
  __shared__ __align__(16) unsigned short Bs[3*2048];
  f32x4 acc[4][2] = {};
  const int tid = threadIdx.x, lane = tid & 63, w = tid >> 6;
  const int wm = w >> 1, wn = w & 1;
  const int fr = lane & 15, fq = lane >> 4;
  const int id  = blockIdx.x;            // 0..511
  const int xcd = id & 7;
  const int lid = id >> 3;               // 0..63
  const int m0 = (xcd*4 + (lid & 3)) * 128;
  const int n0 = (lid >> 2) * 64;
  const int ph = ((fq ^ ((fr + (fr >> 2)) & 3))) * 8;

#define STAGEO(kt, buf) do {                                                        \
    _Pragma("unroll")                                                               \
    for (int i_ = 0; i_ < 2; ++i_){                                                 \
      const int c_ = i_*256 + tid;                                                  \
      const int row_ = c_ >> 2, cd_ = c_ & 3;                                       \
      const int sc_ = ((cd_ ^ ((row_ + (row_ >> 2)) & 3))) << 3;                    \
      const unsigned short* ga_ = Obf + (size_t)(m0 + row_) * 1024 + (kt)*32 + sc_; \
      __builtin_amdgcn_global_load_lds((const __attribute__((address_space(1))) void*)ga_, \
          (__attribute__((address_space(3))) void*)(As + (buf)*4096 + c_*8), 16, 0, 0);    \
    }                                                                               \
    {                                                                               \
      const int c_ = tid;                                                           \
      const int row_ = c_ >> 2, cd_ = c_ & 3;                                       \
      const int sc_ = ((cd_ ^ ((row_ + (row_ >> 2)) & 3))) << 3;                    \
      const unsigned short* gb_ = Wb + (size_t)(n0 + row_) * 1024 + (kt)*32 + sc_;  \
      __builtin_amdgcn_global_load_lds((const __attribute__((address_space(1))) void*)gb_, \
          (__attribute__((address_space(3))) void*)(Bs + (buf)*2048 + c_*8), 16, 0, 0);    \
    }                                                                               \
  } while(0)

  STAGEO(0, 0);
  STAGEO(1, 1);
  for (int t = 0; t < 32; ++t){
    const int cur = t % 3;
    if (t + 2 < 32) STAGEO(t + 2, (t + 2) % 3);
    if (t < 30)       asm volatile("s_waitcnt vmcnt(6)" ::: "memory");
    else if (t == 30) asm volatile("s_waitcnt vmcnt(3)" ::: "memory");
    else              asm volatile("s_waitcnt vmcnt(0)" ::: "memory");
    __builtin_amdgcn_s_barrier();
    asm volatile("" ::: "memory");
    const unsigned short* as = As + cur*4096;
    const unsigned short* bs = Bs + cur*2048;
    short8 af[4], bfv[2];
    #pragma unroll
    for (int mf = 0; mf < 4; ++mf)
      af[mf] = *(const short8*)(as + (wm*64 + mf*16 + fr) * 32 + ph);
    #pragma unroll
    for (int nf = 0; nf < 2; ++nf)
      bfv[nf] = *(const short8*)(bs + (wn*32 + nf*16 + fr) * 32 + ph);
    #pragma unroll
    for (int mf = 0; mf < 4; ++mf)
      #pragma unroll
      for (int nf = 0; nf < 2; ++nf)
        acc[mf][nf] = __builtin_amdgcn_mfma_f32_16x16x32_bf16(af[mf], bfv[nf], acc[mf][nf], 0, 0, 0);
    asm volatile("" ::: "memory");
    __builtin_amdgcn_s_barrier();
  }
#undef STAGEO

  #pragma unroll
  for (int mf = 0; mf < 4; ++mf)
    #pragma unroll
    for (int nf = 0; nf < 2; ++nf){
      const int n = n0 + wn*32 + nf*16 + fr;
      #pragma unroll
      for (int r = 0; r < 4; ++r){
        const int m = m0 + wm*64 + mf*16 + fq*4 + r;
        out[(size_t)m * 1024 + n] = acc[mf][nf][r];
      }
    }
}

extern "C" void kernel_launch(void* const* d_in, const int* in_sizes, int n_in,
                              void* d_out, int out_size, void* d_ws, size_t ws_size,
                              hipStream_t stream) {
  const float* x  = (const float*)d_in[0];
  const int* pos  = (const int*)d_in[1];
  const float* wq = (const float*)d_in[2];
  const float* wk = (const float*)d_in[3];
  const float* wv = (const float*)d_in[4];
  const float* wo = (const float*)d_in[5];
  float* out = (float*)d_out;

  unsigned short* ws = (unsigned short*)d_ws;
  unsigned short* Xb   = ws;                  // 4096x1024
  unsigned short* Wqkv = ws + 4194304UL;      // 3072x1024
  unsigned short* Wo   = ws + 7340032UL;      // 1024x1024
  unsigned short* Qb   = ws + 8388608UL;      // [32][2048][64]
  unsigned short* Kb   = ws + 12582912UL;     // [32][2048][64]
  unsigned short* Vt   = ws + 16777216UL;     // [32][64][2048]
  unsigned short* Ob   = ws + 20971520UL;     // 4096x1024
  float2* tab          = (float2*)(ws + 25165824UL);  // 2048x32 cos/sin (512 KB)

  convert_all<<<4096, 256, 0, stream>>>(x, wq, wk, wv, wo, ws, tab);

  gemm_qkv<<<512, 512, 0, stream>>>(Xb, Wqkv, pos, tab, Qb, Kb, Vt);

  attn_kernel<<<1024, 256, 0, stream>>>(Qb, Kb, Vt, Ob);

  gemm_out<<<512, 256, 0, stream>>>(Ob, Wo, out);
}

// Round 22
// 99.888 us; speedup vs baseline: 1.1215x; 1.0348x over previous
//
#include <hip/hip_runtime.h>
#include <hip/hip_bf16.h>

typedef __attribute__((ext_vector_type(8))) short short8;
typedef __attribute__((ext_vector_type(4))) short short4v;
typedef __attribute__((ext_vector_type(4))) float f32x4;

#define LN10000_DIV32 0.2878231366242558f
#define SCALE_Q_LOG2E 0.18033688011112042f
#define EXP_BIAS 12.0f

__device__ __forceinline__ unsigned short f2bf(float f){
  union { float fv; unsigned u; } a; a.fv = f;
  return (unsigned short)((a.u + 0x7fffu + ((a.u >> 16) & 1u)) >> 16);
}

// ------- convert fp32 -> bf16 (x, W_Q|W_K|W_V, W_O) + RoPE cos/sin table -------
__global__ __launch_bounds__(256) void convert_all(
    const float* __restrict__ x, const float* __restrict__ wq,
    const float* __restrict__ wk, const float* __restrict__ wv,
    const float* __restrict__ wo, unsigned short* __restrict__ dst,
    float2* __restrict__ tab)
{
  size_t t = (size_t)blockIdx.x * 256 + threadIdx.x;
  if (t < 65536UL){
    const int s = (int)(t >> 5), ip = (int)(t & 31);
    float invf = __expf(-(float)ip * LN10000_DIV32);
    float ang = (float)s * invf;
    tab[t] = make_float2(__cosf(ang), __sinf(ang));
  }
  size_t e = t * 8;
  const float* src; size_t off;
  if (e < 4194304UL)      { src = x;  off = e; }
  else if (e < 5242880UL) { src = wq; off = e - 4194304UL; }
  else if (e < 6291456UL) { src = wk; off = e - 5242880UL; }
  else if (e < 7340032UL) { src = wv; off = e - 6291456UL; }
  else                    { src = wo; off = e - 7340032UL; }
  float4 f0 = *(const float4*)(src + off);
  float4 f1 = *(const float4*)(src + off + 4);
  short8 o;
  o[0] = (short)f2bf(f0.x); o[1] = (short)f2bf(f0.y);
  o[2] = (short)f2bf(f0.z); o[3] = (short)f2bf(f0.w);
  o[4] = (short)f2bf(f1.x); o[5] = (short)f2bf(f1.y);
  o[6] = (short)f2bf(f1.z); o[7] = (short)f2bf(f1.w);
  *(short8*)(dst + e) = o;
}

// ---------------- QKV projection: 128x192, BK=64, 8 waves (2Mx4N), 16 waves/CU (R21, frozen) ----------------
__global__ __launch_bounds__(512, 2) void gemm_qkv(
    const unsigned short* __restrict__ Xb, const unsigned short* __restrict__ Wb,
    const int* __restrict__ positions, const float2* __restrict__ tab,
    unsigned short* __restrict__ Qb, unsigned short* __restrict__ Kb,
    unsigned short* __restrict__ Vtb)
{
  __shared__ __align__(16) unsigned short As[2*8192];   // 2 x 128x64 (32 KB)
  __shared__ __align__(16) unsigned short Bs[2*12288];  // 2 x 192x64 (48 KB)
  f32x4 acc[4][3] = {};
  const int tid = threadIdx.x, lane = tid & 63, w = tid >> 6;
  const int wm = w >> 2, wn = w & 3;                    // 2 M-groups x 4 N-groups
  const int fr = lane & 15, fq = lane >> 4;
  const int id  = blockIdx.x;                           // 0..511
  const int xcd = id & 7;
  const int lid = id >> 3;                              // 0..63
  const int m0 = (lid & 31) * 128;
  const int n0 = (xcd*2 + (lid >> 5)) * 192;

#define STAGE_ALL(kt, buf) do {                                                     \
    _Pragma("unroll")                                                               \
    for (int i_ = 0; i_ < 2; ++i_){                    /* A: 1024 chunks */         \
      const int c_ = i_*512 + tid;                                                  \
      const int row_ = c_ >> 3, cd_ = c_ & 7;                                       \
      const int sc_ = (cd_ ^ (row_ & 7)) << 3;                                      \
      const unsigned short* ga_ = Xb + (size_t)(m0 + row_) * 1024 + (kt)*64 + sc_;  \
      __builtin_amdgcn_global_load_lds((const __attribute__((address_space(1))) void*)ga_, \
          (__attribute__((address_space(3))) void*)(As + (buf)*8192 + c_*8), 16, 0, 0);    \
    }                                                                               \
    _Pragma("unroll")                                                               \
    for (int i_ = 0; i_ < 3; ++i_){                    /* B: 1536 chunks */         \
      const int c_ = i_*512 + tid;                                                  \
      const int row_ = c_ >> 3, cd_ = c_ & 7;                                       \
      const int sc_ = (cd_ ^ (row_ & 7)) << 3;                                      \
      const unsigned short* gb_ = Wb + (size_t)(n0 + row_) * 1024 + (kt)*64 + sc_;  \
      __builtin_amdgcn_global_load_lds((const __attribute__((address_space(1))) void*)gb_, \
          (__attribute__((address_space(3))) void*)(Bs + (buf)*12288 + c_*8), 16, 0, 0);   \
    }                                                                               \
  } while(0)

  STAGE_ALL(0, 0);

  const int row_a0 = wm*64 + fr;
  const int row_b0 = wn*48 + fr;

  for (int t = 0; t < 16; ++t){
    const int cur = t & 1;
    if (t + 1 < 16){
      STAGE_ALL(t + 1, cur ^ 1);
      asm volatile("s_waitcnt vmcnt(5)" ::: "memory");
    } else {
      asm volatile("s_waitcnt vmcnt(0)" ::: "memory");
    }
    __builtin_amdgcn_s_barrier();
    asm volatile("" ::: "memory");
    const unsigned short* as = As + cur*8192;
    const unsigned short* bs = Bs + cur*12288;
    short8 af[4], bfv[3];

#define LDA(mf_, kh_) do { \
      const int row_ = row_a0 + (mf_)*16; \
      const int c_ = ((kh_)*4 + fq) ^ (row_ & 7); \
      af[mf_] = *(const short8*)(as + row_*64 + c_*8); } while(0)
#define LDB(nf_, kh_) do { \
      const int row_ = row_b0 + (nf_)*16; \
      const int c_ = ((kh_)*4 + fq) ^ (row_ & 7); \
      bfv[nf_] = *(const short8*)(bs + row_*64 + c_*8); } while(0)

    LDA(0,0); LDA(1,0); LDA(2,0); LDA(3,0);
    LDB(0,0); LDB(1,0); LDB(2,0);
    __builtin_amdgcn_s_setprio(1);
    #pragma unroll
    for (int mf = 0; mf < 4; ++mf)
      #pragma unroll
      for (int nf = 0; nf < 3; ++nf)
        acc[mf][nf] = __builtin_amdgcn_mfma_f32_16x16x32_bf16(af[mf], bfv[nf], acc[mf][nf], 0, 0, 0);
    __builtin_amdgcn_s_setprio(0);

    LDA(0,1); LDA(1,1); LDA(2,1); LDA(3,1);
    LDB(0,1); LDB(1,1); LDB(2,1);
    __builtin_amdgcn_s_setprio(1);
    #pragma unroll
    for (int mf = 0; mf < 4; ++mf)
      #pragma unroll
      for (int nf = 0; nf < 3; ++nf)
        acc[mf][nf] = __builtin_amdgcn_mfma_f32_16x16x32_bf16(af[mf], bfv[nf], acc[mf][nf], 0, 0, 0);
    __builtin_amdgcn_s_setprio(0);
    asm volatile("" ::: "memory");
    __builtin_amdgcn_s_barrier();
#undef LDA
#undef LDB
  }
#undef STAGE_ALL

  #pragma unroll
  for (int mf = 0; mf < 4; ++mf){
    int pm[4];
    #pragma unroll
    for (int r = 0; r < 4; ++r){
      const int m = m0 + wm*64 + mf*16 + fq*4 + r;
      pm[r] = positions[m] & 2047;
    }
    const int mbase = m0 + wm*64 + mf*16 + fq*4;
    const int b = mbase >> 11;
    const int s0 = mbase & 2047;
    #pragma unroll
    for (int nf = 0; nf < 3; ++nf){
      const int n = n0 + wn*48 + nf*16 + fr;
      const int seg = n >> 10;
      const int h = (n & 1023) >> 6, d = n & 63;
      const size_t bh = (size_t)b * 16 + h;
      if (seg == 2){
        short4v pack;
        #pragma unroll
        for (int r = 0; r < 4; ++r)
          pack[r] = (short)f2bf(acc[mf][nf][r]);
        *(short4v*)&Vtb[(bh*64 + d)*2048 + s0] = pack;
      } else {
        const int ip = d >> 1;
        #pragma unroll
        for (int r = 0; r < 4; ++r){
          float v = acc[mf][nf][r];
          float pv = __shfl_xor(v, 1);
          const float2 cs = tab[(pm[r] << 5) + ip];
          float outv = (d & 1) ? (cs.x * v + cs.y * pv)
                               : (cs.x * v - cs.y * pv);
          if (seg == 0) outv *= SCALE_Q_LOG2E;
          const unsigned short ob = f2bf(outv);
          const int s = s0 + r;
          if (seg == 0) Qb[(bh*2048 + s)*64 + d] = ob;
          else          Kb[(bh*2048 + s)*64 + d] = ob;
        }
      }
    }
  }
}

// ---------------- causal flash attention v6: fixed-bias softmax (frozen) ----------------
__global__ __launch_bounds__(256) void attn_kernel(
    const unsigned short* __restrict__ Qb, const unsigned short* __restrict__ Kb,
    const unsigned short* __restrict__ Vtb, unsigned short* __restrict__ Ob)
{
  __shared__ __align__(16) unsigned short Ks[2][4096];
  __shared__ __align__(16) unsigned short Vs[2][4096];
  __shared__ __align__(16) unsigned short Plds[4][16][64];

  const int tid = threadIdx.x, lane = tid & 63, w = tid >> 6;
  const int fr = lane & 15, fq = lane >> 4;

  const int i = blockIdx.x;
  const int bh = (i & 7) | (((i >> 3) & 3) << 3);   // XCD-pinned
  const int tile = 31 - (i >> 5);                   // longest tiles first
  const int b = bh >> 4, h = bh & 15;
  const int q0 = tile * 64 + w * 16;
  const size_t qk_base = (size_t)bh * 2048 * 64;
  const unsigned short* kbase = Kb + qk_base;
  const unsigned short* vbase = Vtb + (size_t)bh * 64 * 2048;

  const unsigned short* qp = Qb + qk_base + (size_t)(q0 + fr) * 64 + fq * 8;
  short8 aq0 = *(const short8*)qp;
  short8 aq1 = *(const short8*)(qp + 32);

  f32x4 accO[4] = {};
  float lrun = 0.f;
  const int qrow = q0 + fr;
  const int nt = tile + 1;
  const int sw3 = (fr & 7) << 2;

#define STAGE_KV(t_, buf_) do {                                                     \
    const int kv0_ = (t_) * 64;                                                     \
    _Pragma("unroll")                                                               \
    for (int ii_ = 0; ii_ < 2; ++ii_){                                              \
      const int chunk_ = ii_ * 256 + tid;                                           \
      const int row_ = chunk_ >> 3, cd_ = chunk_ & 7;                               \
      const int sc_ = (cd_ ^ (row_ & 7)) << 3;                                      \
      const unsigned short* ksrc_ = kbase + (size_t)(kv0_ + row_) * 64 + sc_;       \
      const unsigned short* vsrc_ = vbase + (size_t)row_ * 2048 + kv0_ + sc_;       \
      __builtin_amdgcn_global_load_lds((const __attribute__((address_space(1))) void*)ksrc_, \
          (__attribute__((address_space(3))) void*)(&Ks[buf_][0] + chunk_*8), 16, 0, 0);     \
      __builtin_amdgcn_global_load_lds((const __attribute__((address_space(1))) void*)vsrc_, \
          (__attribute__((address_space(3))) void*)(&Vs[buf_][0] + chunk_*8), 16, 0, 0);     \
    }                                                                               \
  } while(0)

  STAGE_KV(0, 0);
  for (int t = 0; t < nt; ++t){
    const int cur = t & 1;
    const int kv0 = t * 64;
    if (t + 1 < nt){
      STAGE_KV(t + 1, cur ^ 1);
      asm volatile("s_waitcnt vmcnt(4)" ::: "memory");
    } else {
      asm volatile("s_waitcnt vmcnt(0)" ::: "memory");
    }
    __builtin_amdgcn_s_barrier();
    asm volatile("" ::: "memory");
    const unsigned short* ks = &Ks[cur][0];
    const unsigned short* vs = &Vs[cur][0];

    f32x4 sT[4];
    #pragma unroll
    for (int kf = 0; kf < 4; ++kf){
      const int row = kf*16 + fr;
      const int swr = row & 7;
      short8 k0 = *(const short8*)(ks + row*64 + ((fq ^ swr) << 3));
      short8 k1 = *(const short8*)(ks + row*64 + (((4 + fq) ^ swr) << 3));
      f32x4 s = {0.f, 0.f, 0.f, 0.f};
      s = __builtin_amdgcn_mfma_f32_16x16x32_bf16(k0, aq0, s, 0, 0, 0);
      s = __builtin_amdgcn_mfma_f32_16x16x32_bf16(k1, aq1, s, 0, 0, 0);
      sT[kf] = s;
    }
    if (t == nt - 1){
      #pragma unroll
      for (int kf = 0; kf < 4; ++kf)
        #pragma unroll
        for (int r = 0; r < 4; ++r){
          const int kvcol = kv0 + kf*16 + fq*4 + r;
          if (kvcol > qrow) sT[kf][r] = -1e30f;
        }
    }
    float p[4][4];
    float rs = 0.f;
    #pragma unroll
    for (int kf = 0; kf < 4; ++kf)
      #pragma unroll
      for (int r = 0; r < 4; ++r){
        p[kf][r] = __builtin_amdgcn_exp2f(sT[kf][r] - EXP_BIAS);
        rs += p[kf][r];
      }
    rs += __shfl_xor(rs, 16);
    rs += __shfl_xor(rs, 32);
    lrun += rs;
    unsigned* prow = (unsigned*)&Plds[w][fr][0];
    #pragma unroll
    for (int kf = 0; kf < 4; ++kf)
      #pragma unroll
      for (int jj = 0; jj < 2; ++jj){
        unsigned pk;
        asm("v_cvt_pk_bf16_f32 %0, %1, %2" : "=v"(pk) : "v"(p[kf][2*jj]), "v"(p[kf][2*jj+1]));
        prow[(kf*8 + fq*2 + jj) ^ sw3] = pk;
      }
    asm volatile("s_waitcnt lgkmcnt(0)" ::: "memory");
    const unsigned* crow = (const unsigned*)&Plds[w][fr][0];
    short8 ap0 = *(const short8*)&crow[(fq*4) ^ sw3];
    short8 ap1 = *(const short8*)&crow[(16 + fq*4) ^ sw3];
    __builtin_amdgcn_s_setprio(1);
    #pragma unroll
    for (int dblk = 0; dblk < 4; ++dblk){
      const int d = dblk*16 + fr;
      const int swd = d & 7;
      short8 bv0 = *(const short8*)(vs + d*64 + ((fq ^ swd) << 3));
      short8 bv1 = *(const short8*)(vs + d*64 + (((4 + fq) ^ swd) << 3));
      accO[dblk] = __builtin_amdgcn_mfma_f32_16x16x32_bf16(ap0, bv0, accO[dblk], 0, 0, 0);
      accO[dblk] = __builtin_amdgcn_mfma_f32_16x16x32_bf16(ap1, bv1, accO[dblk], 0, 0, 0);
    }
    __builtin_amdgcn_s_setprio(0);
    asm volatile("" ::: "memory");
    __builtin_amdgcn_s_barrier();
  }
#undef STAGE_KV
  float lq[4];
  #pragma unroll
  for (int r = 0; r < 4; ++r)
    lq[r] = __shfl(lrun, fq*4 + r);
  #pragma unroll
  for (int dblk = 0; dblk < 4; ++dblk)
    #pragma unroll
    for (int r = 0; r < 4; ++r){
      const int s = q0 + fq*4 + r;
      const float o = accO[dblk][r] / lq[r];
      Ob[((size_t)b*2048 + s)*1024 + h*64 + dblk*16 + fr] = f2bf(o);
    }
}

// ---------------- output projection v2: 128x64 tiles, BK=64, stage-early counted vmcnt ----------------
// 512 blocks (32m x 16n), 256 threads (4 waves, 2M x 2N, per-wave 64x32 = acc[4][2]).
// LDS 2 x (128x64 + 64x64) = 48 KB -> all 512 blocks co-resident at 2/CU.
// Per K-tile: {STAGE(t+1) -> vmcnt(6) -> barrier -> ds_read+MFMA kh0,kh1 -> end barrier}.
// Zero-conflict swizzle c ^ (row&7) (R15-21 verified). 16 tiles (vs 32 at BK=32):
// half the barrier count, loads waited a full tile after issue.
__global__ __launch_bounds__(256, 2) void gemm_out(
    const unsigned short* __restrict__ Obf, const unsigned short* __restrict__ Wb,
    float* __restrict__ out)
{
  __shared__ __align__(16) unsigned short As[2*8192];   // 2 x 128x64 (32 KB)
  __shared__ __align__(16) unsigned short Bs[2*4096];   // 2 x 64x64 (16 KB)
  f32x4 acc[4][2] = {};
  const int tid = threadIdx.x, lane = tid & 63, w = tid >> 6;
  const int wm = w >> 1, wn = w & 1;
  const int fr = lane & 15, fq = lane >> 4;
  const int id  = blockIdx.x;            // 0..511
  const int xcd = id & 7;
  const int lid = id >> 3;               // 0..63
  const int m0 = (xcd*4 + (lid & 3)) * 128;
  const int n0 = (lid >> 2) * 64;

#define STAGEO(kt, buf) do {                                                        \
    _Pragma("unroll")                                                               \
    for (int i_ = 0; i_ < 4; ++i_){                    /* A: 1024 chunks */         \
      const int c_ = i_*256 + tid;                                                  \
      const int row_ = c_ >> 3, cd_ = c_ & 7;                                       \
      const int sc_ = (cd_ ^ (row_ & 7)) << 3;                                      \
      const unsigned short* ga_ = Obf + (size_t)(m0 + row_) * 1024 + (kt)*64 + sc_; \
      __builtin_amdgcn_global_load_lds((const __attribute__((address_space(1))) void*)ga_, \
          (__attribute__((address_space(3))) void*)(As + (buf)*8192 + c_*8), 16, 0, 0);    \
    }                                                                               \
    _Pragma("unroll")                                                               \
    for (int i_ = 0; i_ < 2; ++i_){                    /* B: 512 chunks */          \
      const int c_ = i_*256 + tid;                                                  \
      const int row_ = c_ >> 3, cd_ = c_ & 7;                                       \
      const int sc_ = (cd_ ^ (row_ & 7)) << 3;                                      \
      const unsigned short* gb_ = Wb + (size_t)(n0 + row_) * 1024 + (kt)*64 + sc_;  \
      __builtin_amdgcn_global_load_lds((const __attribute__((address_space(1))) void*)gb_, \
          (__attribute__((address_space(3))) void*)(Bs + (buf)*4096 + c_*8), 16, 0, 0);    \
    }                                                                               \
  } while(0)

  STAGEO(0, 0);                          // prologue: tile 0

  const int row_a0 = wm*64 + fr;
  const int row_b0 = wn*32 + fr;

  for (int t = 0; t < 16; ++t){
    const int cur = t & 1;
    if (t + 1 < 16){
      STAGEO(t + 1, cur ^ 1);            // safe: end-barrier of iter t-1 passed
      asm volatile("s_waitcnt vmcnt(6)" ::: "memory");   // tile t's 6 loads done
    } else {
      asm volatile("s_waitcnt vmcnt(0)" ::: "memory");
    }
    __builtin_amdgcn_s_barrier();
    asm volatile("" ::: "memory");
    const unsigned short* as = As + cur*8192;
    const unsigned short* bs = Bs + cur*4096;
    short8 af[4], bfv[2];

#define LDA(mf_, kh_) do { \
      const int row_ = row_a0 + (mf_)*16; \
      const int c_ = ((kh_)*4 + fq) ^ (row_ & 7); \
      af[mf_] = *(const short8*)(as + row_*64 + c_*8); } while(0)
#define LDB(nf_, kh_) do { \
      const int row_ = row_b0 + (nf_)*16; \
      const int c_ = ((kh_)*4 + fq) ^ (row_ & 7); \
      bfv[nf_] = *(const short8*)(bs + row_*64 + c_*8); } while(0)

    // ---- k-half 0 ----
    LDA(0,0); LDA(1,0); LDA(2,0); LDA(3,0);
    LDB(0,0); LDB(1,0);
    __builtin_amdgcn_s_setprio(1);
    #pragma unroll
    for (int mf = 0; mf < 4; ++mf)
      #pragma unroll
      for (int nf = 0; nf < 2; ++nf)
        acc[mf][nf] = __builtin_amdgcn_mfma_f32_16x16x32_bf16(af[mf], bfv[nf], acc[mf][nf], 0, 0, 0);
    __builtin_amdgcn_s_setprio(0);

    // ---- k-half 1 ----
    LDA(0,1); LDA(1,1); LDA(2,1); LDA(3,1);
    LDB(0,1); LDB(1,1);
    __builtin_amdgcn_s_setprio(1);
    #pragma unroll
    for (int mf = 0; mf < 4; ++mf)
      #pragma unroll
      for (int nf = 0; nf < 2; ++nf)
        acc[mf][nf] = __builtin_amdgcn_mfma_f32_16x16x32_bf16(af[mf], bfv[nf], acc[mf][nf], 0, 0, 0);
    __builtin_amdgcn_s_setprio(0);
    asm volatile("" ::: "memory");
    __builtin_amdgcn_s_barrier();        // end barrier: buf[cur] reusable
#undef LDA
#undef LDB
  }
#undef STAGEO

  #pragma unroll
  for (int mf = 0; mf < 4; ++mf)
    #pragma unroll
    for (int nf = 0; nf < 2; ++nf){
      const int n = n0 + wn*32 + nf*16 + fr;
      #pragma unroll
      for (int r = 0; r < 4; ++r){
        const int m = m0 + wm*64 + mf*16 + fq*4 + r;
        out[(size_t)m * 1024 + n] = acc[mf][nf][r];
      }
    }
}

extern "C" void kernel_launch(void* const* d_in, const int* in_sizes, int n_in,
                              void* d_out, int out_size, void* d_ws, size_t ws_size,
                              hipStream_t stream) {
  const float* x  = (const float*)d_in[0];
  const int* pos  = (const int*)d_in[1];
  const float* wq = (const float*)d_in[2];
  const float* wk = (const float*)d_in[3];
  const float* wv = (const float*)d_in[4];
  const float* wo = (const float*)d_in[5];
  float* out = (float*)d_out;

  unsigned short* ws = (unsigned short*)d_ws;
  unsigned short* Xb   = ws;                  // 4096x1024
  unsigned short* Wqkv = ws + 4194304UL;      // 3072x1024
  unsigned short* Wo   = ws + 7340032UL;      // 1024x1024
  unsigned short* Qb   = ws + 8388608UL;      // [32][2048][64]
  unsigned short* Kb   = ws + 12582912UL;     // [32][2048][64]
  unsigned short* Vt   = ws + 16777216UL;     // [32][64][2048]
  unsigned short* Ob   = ws + 20971520UL;     // 4096x1024
  float2* tab          = (float2*)(ws + 25165824UL);  // 2048x32 cos/sin (512 KB)

  convert_all<<<4096, 256, 0, stream>>>(x, wq, wk, wv, wo, ws, tab);

  gemm_qkv<<<512, 512, 0, stream>>>(Xb, Wqkv, pos, tab, Qb, Kb, Vt);

  attn_kernel<<<1024, 256, 0, stream>>>(Qb, Kb, Vt, Ob);

  gemm_out<<<512, 256, 0, stream>>>(Ob, Wo, out);
}